// Round 20
// baseline (520.246 us; speedup 1.0000x reference)
//
#include <hip/hip_runtime.h>
#include <hip/hip_bf16.h>
#include <cmath>

typedef float f32x2 __attribute__((ext_vector_type(2)));
typedef float f32x4 __attribute__((ext_vector_type(4)));
typedef float f32x16 __attribute__((ext_vector_type(16)));
typedef short bf16x8 __attribute__((ext_vector_type(8)));
typedef const __attribute__((address_space(1))) unsigned int* gas_t;
typedef __attribute__((address_space(3))) unsigned int* las_t;

#define GLOAD16(g, l) __builtin_amdgcn_global_load_lds((gas_t)(const void*)(g), (las_t)(void*)(l), 16, 0, 0)

#define LOG2E 1.4426950408889634f
#define MASKC (-144.2695040888963f)
#define SL2E  (0.17677669529663687f * 1.4426950408889634f)

static __device__ __forceinline__ float bf2f(unsigned short u){
  return __uint_as_float(((unsigned)u) << 16);
}
static __device__ __forceinline__ unsigned short f2bf(float f){
  unsigned u = __float_as_uint(f);
  unsigned r = u + 0x7FFFu + ((u >> 16) & 1u);
  return (unsigned short)(r >> 16);
}
static __device__ __forceinline__ unsigned packbf(float a, float b){
  union { __hip_bfloat162 h; unsigned u; } cv;
  cv.h = __float22bfloat162_rn(make_float2(a, b));
  return cv.u;
}
static __device__ __forceinline__ f32x16 zero16(){
  f32x16 z;
  #pragma unroll
  for (int i = 0; i < 16; i++) z[i] = 0.f;
  return z;
}

// ---------------- zero pad slots (tile t=10) of qs2/ks2/vt2 ----------------
__global__ __launch_bounds__(256) void padzero_kernel(unsigned short* __restrict__ qs2,
                                                      unsigned short* __restrict__ ks2,
                                                      unsigned short* __restrict__ vt2){
  const int wh = blockIdx.x;
  uint4 z = make_uint4(0, 0, 0, 0);
  const size_t base = (size_t)wh * 11264 + 10 * 1024;
  for (int i = threadIdx.x; i < 384; i += 256){
    int arr = i >> 7, slot = i & 127;
    unsigned short* p = (arr == 0 ? qs2 : (arr == 1 ? ks2 : vt2));
    *(uint4*)(p + base + slot * 8) = z;
  }
}

// ---------------- tiled weight transpose: out[n][k] = bf16(in[k][n]) ----------------
__global__ __launch_bounds__(256) void wconv2_kernel(const float* __restrict__ in,
                                                     unsigned short* __restrict__ out,
                                                     int K, int N){
  __shared__ unsigned short t[32][33];
  int tx = threadIdx.x & 31, ty = threadIdx.x >> 5;
  int n0 = blockIdx.x * 32, k0 = blockIdx.y * 32;
  #pragma unroll
  for (int i = 0; i < 4; i++)
    t[ty + 8 * i][tx] = f2bf(in[(size_t)(k0 + ty + 8 * i) * N + n0 + tx]);
  __syncthreads();
  #pragma unroll
  for (int i = 0; i < 4; i++)
    out[(size_t)(n0 + ty + 8 * i) * K + k0 + tx] = t[tx][ty + 8 * i];
}

// ---------------- biasF prep: fragment-packed BF16 bias+mask, log2-domain ----------------
__global__ __launch_bounds__(256) void biasprep3_kernel(const float* __restrict__ rel,
                                                        unsigned short* __restrict__ biasF16){
  const int plane = blockIdx.y;            // cls*12+h
  const int cls = plane / 12, h = plane - cls * 12;
  const int qt = blockIdx.x / 11, t = blockIdx.x - qt * 11;
  const int tid = threadIdx.x;
  const int lane = tid >> 2, rb = (tid & 3) * 4;
  const int q = qt * 32 + (lane & 31);
  float v[4];
  #pragma unroll
  for (int j = 0; j < 4; j++){
    const int r = rb + j;
    const int mm = t * 32 + (r & 3) + 8 * (r >> 2) + 4 * (lane >> 5);
    float val;
    if (q >= 343 || mm >= 343) val = -1e30f;
    else {
      int qi0 = q / 49, qr = q - qi0 * 49, qi1 = qr / 7, qi2 = qr - qi1 * 7;
      int mi0 = mm / 49, mr = mm - mi0 * 49, mi1 = mr / 7, mi2 = mr - mi1 * 7;
      int idx = 13 * (qi0 - mi0 + 6) + (qi1 - mi1 + 6) + (qi2 - mi2);
      if (idx < 0) idx += 2197;
      val = rel[idx * 12 + h] * LOG2E;
      int az = (cls & 4) ? (qi0 < 4 ? 1 : 2) : 0;
      int ax = (cls & 2) ? (qi1 < 4 ? 1 : 2) : 0;
      int ay = (cls & 1) ? (qi2 < 4 ? 1 : 2) : 0;
      int bz = (cls & 4) ? (mi0 < 4 ? 1 : 2) : 0;
      int bx = (cls & 2) ? (mi1 < 4 ? 1 : 2) : 0;
      int by = (cls & 1) ? (mi2 < 4 ? 1 : 2) : 0;
      if (az * 9 + ax * 3 + ay != bz * 9 + bx * 3 + by) val += MASKC;
    }
    v[j] = val;
  }
  uint2 st;
  st.x = packbf(v[0], v[1]);
  st.y = packbf(v[2], v[3]);
  *(uint2*)(biasF16 + (((size_t)plane * 121 + blockIdx.x) * 64 + lane) * 16 + rb) = st;
}

// ---------------- LayerNorm (+optional shift+window-partition gather), vectorized ----------------
template<int MODE>
__global__ __launch_bounds__(256) void ln_kernel(const float* __restrict__ in,
                                                 const float* __restrict__ g,
                                                 const float* __restrict__ bta,
                                                 unsigned short* __restrict__ out){
  int wave = threadIdx.x >> 6, lane = threadIdx.x & 63;
  int row = blockIdx.x * 4 + wave;          // < 43904
  size_t srow;
  if (MODE == 0){
    int win = row / 343, n = row - win * 343;
    int b = win >> 6, w64 = win & 63;
    int zw = w64 >> 5, xw = (w64 >> 3) & 3, yw = w64 & 7;
    int i0 = n / 49, nr = n - i0 * 49, i1 = nr / 7, i2 = nr - i1 * 7;
    int zs = zw * 7 + i0 + 3; if (zs >= 14) zs -= 14;
    int xs = xw * 7 + i1 + 3; if (xs >= 28) xs -= 28;
    int ys = yw * 7 + i2 + 3; if (ys >= 56) ys -= 56;
    srow = (size_t)b * 21952 + zs * 1568 + xs * 56 + ys;
  } else {
    srow = (size_t)row;
  }
  const float* p = in + srow * 384;
  float v[6]; float s = 0.f;
  #pragma unroll
  for (int i = 0; i < 3; i++){
    f32x2 t = *(const f32x2*)(p + lane * 2 + i * 128);
    v[2 * i] = t[0]; v[2 * i + 1] = t[1];
    s += t[0] + t[1];
  }
  #pragma unroll
  for (int off = 32; off >= 1; off >>= 1) s += __shfl_xor(s, off);
  float mean = s * (1.f / 384.f);
  float vs = 0.f;
  #pragma unroll
  for (int i = 0; i < 6; i++){ float d = v[i] - mean; vs += d * d; }
  #pragma unroll
  for (int off = 32; off >= 1; off >>= 1) vs += __shfl_xor(vs, off);
  float rstd = rsqrtf(vs * (1.f / 384.f) + 1e-5f);
  unsigned short* o = out + (size_t)row * 384;
  #pragma unroll
  for (int i = 0; i < 3; i++){
    const int c = lane * 2 + i * 128;
    f32x2 gg = *(const f32x2*)(g + c);
    f32x2 bb = *(const f32x2*)(bta + c);
    float a0 = (v[2 * i] - mean) * rstd * gg[0] + bb[0];
    float a1 = (v[2 * i + 1] - mean) * rstd * gg[1] + bb[1];
    *(unsigned*)(&o[c]) = packbf(a0, a1);
  }
}

// ---------------- GEMM: C[M,N] = A[M,K] @ Bt[N,K]^T, operand-swapped MFMA, BK=128 ----------------
// BK=128 (64 KB LDS): 64 MFMAs per barrier-pair. Occupancy is register-capped at
// ~2 blocks/CU anyway (129-256 reg bracket), so the extra LDS is free; barrier pairs
// halve vs BK=64 (the one measured-positive K-loop knob). nt store only on EPI3.
template<int EPI>
__global__ __launch_bounds__(256, 4) void gemm2(
    const unsigned short* __restrict__ A,
    const unsigned short* __restrict__ Bt,
    const float* __restrict__ bias,
    const float* __restrict__ resid,
    void* __restrict__ outp,
    unsigned short* __restrict__ oq,
    unsigned short* __restrict__ ok,
    unsigned short* __restrict__ ov,
    int K, int ldc, int nt_){
  __shared__ unsigned short As[16384];   // 32 KB: 4 ksub x 8 chunks x (16 rows x 32 k)
  __shared__ unsigned short Bs[16384];
  const int nwg = gridDim.x;
  const int qq = nwg >> 3, rr = nwg & 7;
  const int xcd = blockIdx.x & 7, pos = blockIdx.x >> 3;
  const int wgid = (xcd < rr ? xcd * (qq + 1) : rr * (qq + 1) + (xcd - rr) * qq) + pos;
  const int mtile = wgid / nt_, ntile = wgid - mtile * nt_;
  const int r0 = mtile * 128, c0 = ntile * 128;

  const int tid = threadIdx.x, lane = tid & 63, wave = tid >> 6;
  const int wr = (wave >> 1) * 64, wc = (wave & 1) * 64;
  f32x4 acc[4][4];
  #pragma unroll
  for (int mi = 0; mi < 4; mi++)
    #pragma unroll
    for (int ni = 0; ni < 4; ni++) acc[mi][ni] = f32x4{0.f, 0.f, 0.f, 0.f};

  const int srow = lane >> 2;
  const int koff = ((lane & 3) ^ ((lane >> 3) & 3)) * 8;
  const int kkey = (lane >> 1) & 3;

  for (int k0 = 0; k0 < K; k0 += 128){
    __syncthreads();
    #pragma unroll
    for (int i = 0; i < 16; i++){
      const int id = wave + i * 4;            // 0..63
      const int arr = id >> 5;                // 0=A, 1=B
      const int within = id & 31;
      const int ksub = within >> 3;           // 0..3
      const int sub = within & 7;             // 0..7
      const unsigned short* g = (arr ? Bt : A)
          + (size_t)((arr ? c0 : r0) + sub * 16 + srow) * K + k0 + ksub * 32 + koff;
      unsigned short* dst = (arr ? Bs : As) + ksub * 4096 + sub * 512;
      GLOAD16(g, dst);
    }
    __syncthreads();
    #pragma unroll
    for (int ks = 0; ks < 4; ks++){
      bf16x8 af[4], bfr[4];
      #pragma unroll
      for (int mi = 0; mi < 4; mi++)
        af[mi] = *(const bf16x8*)(&As[ks * 4096 + (wr + mi * 16 + (lane & 15)) * 32 + (((lane >> 4) ^ kkey) * 8)]);
      #pragma unroll
      for (int ni = 0; ni < 4; ni++)
        bfr[ni] = *(const bf16x8*)(&Bs[ks * 4096 + (wc + ni * 16 + (lane & 15)) * 32 + (((lane >> 4) ^ kkey) * 8)]);
      #pragma unroll
      for (int mi = 0; mi < 4; mi++)
        #pragma unroll
        for (int ni = 0; ni < 4; ni++)
          acc[mi][ni] = __builtin_amdgcn_mfma_f32_16x16x32_bf16(bfr[ni], af[mi], acc[mi][ni], 0, 0, 0);
    }
  }

  // ---- direct-from-acc epilogue: thread owns (row, 4 consecutive cols) per (mi,ni) ----
  const int lrow = lane & 15;
  const int cq4  = (lane >> 4) << 2;
  #pragma unroll
  for (int mi = 0; mi < 4; mi++){
    const int row = r0 + wr + mi * 16 + lrow;
    int win, m, t, mloc, vh2;
    size_t sdst;
    if (EPI == 0 || EPI == 1){ win = row / 343; m = row - win * 343; }
    if (EPI == 0){
      t = m >> 5; mloc = m & 31;
      vh2 = ((m >> 4) & 1) * 512 + ((m >> 3) & 1) * 256 + (m & 7);
    }
    if (EPI == 1){
      const int b = win >> 6, w64 = win & 63;
      const int zw = w64 >> 5, xw = (w64 >> 3) & 3, yw = w64 & 7;
      const int i0 = m / 49, nr = m - i0 * 49, i1 = nr / 7, i2 = nr - i1 * 7;
      int zf = zw * 7 + i0 + 3; if (zf >= 14) zf -= 14;
      int xf = xw * 7 + i1 + 3; if (xf >= 28) xf -= 28;
      int yf = yw * 7 + i2 + 3; if (yf >= 56) yf -= 56;
      sdst = ((size_t)b * 21952 + zf * 1568 + xf * 56 + yf) * 384;
    }
    #pragma unroll
    for (int ni = 0; ni < 4; ni++){
      const int colb = c0 + wc + ni * 16 + cq4;      // 4 consecutive cols
      float v[4];
      #pragma unroll
      for (int j = 0; j < 4; j++) v[j] = acc[mi][ni][j] + bias[colb + j];
      if (EPI == 2){
        #pragma unroll
        for (int j = 0; j < 4; j++)
          v[j] = v[j] * __builtin_amdgcn_rcpf(1.0f + exp2f(v[j] * -2.4554669f));
        uint2 st; st.x = packbf(v[0], v[1]); st.y = packbf(v[2], v[3]);
        *(uint2*)((unsigned short*)outp + (size_t)row * ldc + colb) = st;
      } else if (EPI == 3){
        const float* rsd = resid + (size_t)row * ldc + colb;
        f32x4 q = *(const f32x4*)rsd;
        f32x4 o4; o4[0] = v[0] + q[0]; o4[1] = v[1] + q[1];
        o4[2] = v[2] + q[2]; o4[3] = v[3] + q[3];
        __builtin_nontemporal_store(o4, (f32x4*)((float*)outp + (size_t)row * ldc + colb));
      } else if (EPI == 1){
        const float* rsd = resid + sdst + colb;
        f32x4 q = *(const f32x4*)rsd;
        f32x4 o4; o4[0] = v[0] + q[0]; o4[1] = v[1] + q[1];
        o4[2] = v[2] + q[2]; o4[3] = v[3] + q[3];
        *(f32x4*)((float*)outp + sdst + colb) = o4;
      } else { // EPI == 0
        if (c0 < 384){
          #pragma unroll
          for (int j = 0; j < 4; j++) v[j] *= SL2E;
          const int d = colb, h = d >> 5, dd = d & 31;
          const size_t off = (size_t)(win * 12 + h) * 11264
              + (size_t)(t * 1024 + ((dd >> 4) & 1) * 512 + ((dd >> 3) & 1) * 256 + mloc * 8 + (dd & 7));
          uint2 st; st.x = packbf(v[0], v[1]); st.y = packbf(v[2], v[3]);
          *(uint2*)(oq + off) = st;
        } else if (c0 < 768){
          const int d = colb - 384, h = d >> 5, dd = d & 31;
          const size_t off = (size_t)(win * 12 + h) * 11264
              + (size_t)(t * 1024 + ((dd >> 4) & 1) * 512 + ((dd >> 3) & 1) * 256 + mloc * 8 + (dd & 7));
          uint2 st; st.x = packbf(v[0], v[1]); st.y = packbf(v[2], v[3]);
          *(uint2*)(ok + off) = st;
        } else {
          const int d = colb - 768, h = d >> 5, dd = d & 31;
          const size_t off = (size_t)(win * 12 + h) * 11264 + (size_t)(t * 1024 + vh2);
          #pragma unroll
          for (int j = 0; j < 4; j++)
            ov[off + (size_t)(dd + j) * 8] = f2bf(v[j]);
        }
      }
    }
  }
}

// ---------------- MFMA attention v4: bf16 bias/mask unpacked as MFMA C-in; in-reg P ----
__global__ __launch_bounds__(256, 4) void attn4_kernel(
    const unsigned short* __restrict__ qs2,
    const unsigned short* __restrict__ ks2,
    const unsigned short* __restrict__ vt2,
    const unsigned short* __restrict__ biasF16,
    unsigned short* __restrict__ out){
  __shared__ unsigned short Ks[11264];     // 22 KB, chunk-packed
  const int wh = blockIdx.x;
  const int win = wh / 12, h = wh - win * 12;
  const int tid = threadIdx.x, wave = tid >> 6, lane = tid & 63;
  const int ln = lane & 31, hh = lane >> 5;

  const unsigned short* ksrc = ks2 + (size_t)wh * 11264;
  for (int c = wave; c < 22; c += 4)
    GLOAD16(ksrc + c * 512 + lane * 8, &Ks[c * 512]);

  const int w64 = win & 63;
  const int cls = (((w64 >> 5) & 1) ? 4 : 0) | ((((w64 >> 3) & 3) == 3) ? 2 : 0) | (((w64 & 7) == 7) ? 1 : 0);
  __syncthreads();

  const unsigned short* qbase = qs2 + (size_t)wh * 11264;
  const unsigned short* vbase = vt2 + (size_t)wh * 11264;
  const unsigned short* bbase = biasF16 + (size_t)(cls * 12 + h) * 123904 + lane * 16;

  for (int qt = wave; qt < 11; qt += 4){
    const bf16x8 bq0 = *(const bf16x8*)(qbase + qt * 1024 + hh * 256 + ln * 8);
    const bf16x8 bq1 = *(const bf16x8*)(qbase + qt * 1024 + 512 + hh * 256 + ln * 8);
    const unsigned short* brow = bbase + (size_t)qt * 11264;   // 11 tiles x 1024 ushort

    f32x16 o = zero16();
    float sum = 0.f;
    // prefetch t=0
    bf16x8 nbv0 = *(const bf16x8*)(vbase + hh * 256 + ln * 8);
    bf16x8 nbv1 = *(const bf16x8*)(vbase + 512 + hh * 256 + ln * 8);
    uint4 nbw0 = *(const uint4*)(brow);
    uint4 nbw1 = *(const uint4*)(brow + 8);

    for (int t = 0; t < 11; t++){
      const bf16x8 bv0 = nbv0, bv1 = nbv1;
      unsigned w[8];
      w[0] = nbw0.x; w[1] = nbw0.y; w[2] = nbw0.z; w[3] = nbw0.w;
      w[4] = nbw1.x; w[5] = nbw1.y; w[6] = nbw1.z; w[7] = nbw1.w;
      if (t < 10){
        const unsigned short* vnext = vbase + (t + 1) * 1024;
        nbv0 = *(const bf16x8*)(vnext + hh * 256 + ln * 8);
        nbv1 = *(const bf16x8*)(vnext + 512 + hh * 256 + ln * 8);
        nbw0 = *(const uint4*)(brow + (t + 1) * 1024);
        nbw1 = *(const uint4*)(brow + (t + 1) * 1024 + 8);
      }
      f32x16 acc;                            // C-in = bias + mask (log2-domain), bf16-unpacked
      #pragma unroll
      for (int j = 0; j < 8; j++){
        acc[2 * j]     = __uint_as_float(w[j] << 16);
        acc[2 * j + 1] = __uint_as_float(w[j] & 0xffff0000u);
      }
      const bf16x8 ka0 = *(const bf16x8*)(&Ks[t * 1024 + hh * 256 + ln * 8]);
      const bf16x8 ka1 = *(const bf16x8*)(&Ks[t * 1024 + 512 + hh * 256 + ln * 8]);
      acc = __builtin_amdgcn_mfma_f32_32x32x16_bf16(ka0, bq0, acc, 0, 0, 0);
      acc = __builtin_amdgcn_mfma_f32_32x32x16_bf16(ka1, bq1, acc, 0, 0, 0);

      float pv[16];
      #pragma unroll
      for (int r = 0; r < 16; r++){
        const float e = exp2f(acc[r]);
        sum += e;
        pv[r] = e;
      }
      // in-register P -> A-frag via cvt_pk + permlane32_swap (T12)
      unsigned a0 = packbf(pv[0], pv[1]),  b0 = packbf(pv[4], pv[5]);
      unsigned a1 = packbf(pv[2], pv[3]),  b1 = packbf(pv[6], pv[7]);
      unsigned a2 = packbf(pv[8], pv[9]),  b2 = packbf(pv[12], pv[13]);
      unsigned a3 = packbf(pv[10], pv[11]), b3 = packbf(pv[14], pv[15]);
      asm volatile("v_permlane32_swap_b32 %0, %1" : "+v"(a0), "+v"(b0));
      asm volatile("v_permlane32_swap_b32 %0, %1" : "+v"(a1), "+v"(b1));
      asm volatile("v_permlane32_swap_b32 %0, %1" : "+v"(a2), "+v"(b2));
      asm volatile("v_permlane32_swap_b32 %0, %1" : "+v"(a3), "+v"(b3));
      union { unsigned u[4]; bf16x8 v; } p0c, p1c;
      p0c.u[0] = a0; p0c.u[1] = a1; p0c.u[2] = b0; p0c.u[3] = b1;
      p1c.u[0] = a2; p1c.u[1] = a3; p1c.u[2] = b2; p1c.u[3] = b3;
      o = __builtin_amdgcn_mfma_f32_32x32x16_bf16(p0c.v, bv0, o, 0, 0, 0);
      o = __builtin_amdgcn_mfma_f32_32x32x16_bf16(p1c.v, bv1, o, 0, 0, 0);
    }
    sum += __shfl_xor(sum, 32);
    const float inv = 1.f / sum;   // lane ln holds inv for q-local = ln
    #pragma unroll
    for (int r = 0; r < 16; r++){
      const int qloc = (r & 3) + 8 * (r >> 2) + 4 * hh;
      const float iv = __shfl(inv, qloc);
      const int qg = qt * 32 + qloc;
      if (qg < 343)
        out[((size_t)win * 343 + qg) * 384 + h * 32 + ln] = f2bf(o[r] * iv);
    }
  }
}

// ---------------- host launcher ----------------
extern "C" void kernel_launch(void* const* d_in, const int* in_sizes, int n_in,
                              void* d_out, int out_size, void* d_ws, size_t ws_size,
                              hipStream_t stream){
  const float* x      = (const float*)d_in[0];
  const float* n1g    = (const float*)d_in[1];
  const float* n1b    = (const float*)d_in[2];
  const float* qkv_w  = (const float*)d_in[3];
  const float* qkv_b  = (const float*)d_in[4];
  const float* proj_w = (const float*)d_in[5];
  const float* proj_b = (const float*)d_in[6];
  const float* rel    = (const float*)d_in[7];
  const float* n2g    = (const float*)d_in[8];
  const float* n2b    = (const float*)d_in[9];
  const float* fc1_w  = (const float*)d_in[10];
  const float* fc1_b  = (const float*)d_in[11];
  const float* fc2_w  = (const float*)d_in[12];
  const float* fc2_b  = (const float*)d_in[13];
  float* out = (float*)d_out;

  char* ws = (char*)d_ws;
  // Region plan (bytes), high-water 239,566,848:
  // [0, 33.7M)            w_win bf16 [43904][384]      -- reused as hidden bf16 (0..134.9M)
  // [33.7M, 68.3M)        qs2 ; [68.3M, 102.9M) ks2 ; [102.9M, 137.5M) vt2   -- dead after attn
  // [134.9M, 202.3M)      x2 f32 (written post-attn); pre-attn holds biasF16 @137.5M (23.8MB)
  // [202.3M, 236.0M)      att bf16 -- reused as ln2
  // [236.0M, 239.6M)      bf16 transposed weights
  // All attn-read regions (incl. pads) rewritten EVERY call.
  unsigned short* w_win  = (unsigned short*)(ws + 0);
  unsigned short* hidden = (unsigned short*)(ws + 0);
  unsigned short* qs2    = (unsigned short*)(ws + 33718272ull);
  unsigned short* ks2    = (unsigned short*)(ws + 68321280ull);
  unsigned short* vt2    = (unsigned short*)(ws + 102924288ull);
  float*          x2     = (float*)(ws + 134873088ull);
  unsigned short* biasF16= (unsigned short*)(ws + 137527296ull);  // 23,789,568 B
  unsigned short* att    = (unsigned short*)(ws + 202309632ull);
  unsigned short* ln2    = att;
  unsigned short* wt_qkv = (unsigned short*)(ws + 236027904ull);
  unsigned short* wt_prj = (unsigned short*)(ws + 236912640ull);
  unsigned short* wt_fc1 = (unsigned short*)(ws + 237207552ull);
  unsigned short* wt_fc2 = (unsigned short*)(ws + 238387200ull);

  wconv2_kernel<<<dim3(36, 12), 256, 0, stream>>>(qkv_w, wt_qkv, 384, 1152);
  wconv2_kernel<<<dim3(12, 12), 256, 0, stream>>>(proj_w, wt_prj, 384, 384);
  wconv2_kernel<<<dim3(48, 12), 256, 0, stream>>>(fc1_w, wt_fc1, 384, 1536);
  wconv2_kernel<<<dim3(12, 48), 256, 0, stream>>>(fc2_w, wt_fc2, 1536, 384);
  biasprep3_kernel<<<dim3(121, 96), 256, 0, stream>>>(rel, biasF16);
  padzero_kernel<<<1536, 256, 0, stream>>>(qs2, ks2, vt2);

  ln_kernel<0><<<10976, 256, 0, stream>>>(x, n1g, n1b, w_win);
  gemm2<0><<<343 * 9, 256, 0, stream>>>(w_win, wt_qkv, qkv_b, nullptr, nullptr,
                                        qs2, ks2, vt2, 384, 0, 9);
  attn4_kernel<<<1536, 256, 0, stream>>>(qs2, ks2, vt2, biasF16, att);
  gemm2<1><<<343 * 3, 256, 0, stream>>>(att, wt_prj, proj_b, x, x2,
                                        nullptr, nullptr, nullptr, 384, 384, 3);
  ln_kernel<1><<<10976, 256, 0, stream>>>(x2, n2g, n2b, ln2);
  gemm2<2><<<343 * 12, 256, 0, stream>>>(ln2, wt_fc1, fc1_b, nullptr, hidden,
                                         nullptr, nullptr, nullptr, 384, 1536, 12);
  gemm2<3><<<343 * 3, 256, 0, stream>>>(hidden, wt_fc2, fc2_b, x2, out,
                                        nullptr, nullptr, nullptr, 1536, 384, 3);
}

// Round 21
// 446.416 us; speedup vs baseline: 1.1654x; 1.1654x over previous
//
#include <hip/hip_runtime.h>
#include <hip/hip_bf16.h>
#include <cmath>

typedef float f32x2 __attribute__((ext_vector_type(2)));
typedef float f32x4 __attribute__((ext_vector_type(4)));
typedef float f32x16 __attribute__((ext_vector_type(16)));
typedef short bf16x8 __attribute__((ext_vector_type(8)));
typedef const __attribute__((address_space(1))) unsigned int* gas_t;
typedef __attribute__((address_space(3))) unsigned int* las_t;

#define GLOAD16(g, l) __builtin_amdgcn_global_load_lds((gas_t)(const void*)(g), (las_t)(void*)(l), 16, 0, 0)

#define LOG2E 1.4426950408889634f
#define MASKC (-144.2695040888963f)
#define SL2E  (0.17677669529663687f * 1.4426950408889634f)

static __device__ __forceinline__ float bf2f(unsigned short u){
  return __uint_as_float(((unsigned)u) << 16);
}
static __device__ __forceinline__ unsigned short f2bf(float f){
  unsigned u = __float_as_uint(f);
  unsigned r = u + 0x7FFFu + ((u >> 16) & 1u);
  return (unsigned short)(r >> 16);
}
static __device__ __forceinline__ unsigned packbf(float a, float b){
  union { __hip_bfloat162 h; unsigned u; } cv;
  cv.h = __float22bfloat162_rn(make_float2(a, b));
  return cv.u;
}
static __device__ __forceinline__ f32x16 zero16(){
  f32x16 z;
  #pragma unroll
  for (int i = 0; i < 16; i++) z[i] = 0.f;
  return z;
}

// ---------------- zero pad slots (tile t=10) of qs2/ks2/vt2 ----------------
__global__ __launch_bounds__(256) void padzero_kernel(unsigned short* __restrict__ qs2,
                                                      unsigned short* __restrict__ ks2,
                                                      unsigned short* __restrict__ vt2){
  const int wh = blockIdx.x;
  uint4 z = make_uint4(0, 0, 0, 0);
  const size_t base = (size_t)wh * 11264 + 10 * 1024;
  for (int i = threadIdx.x; i < 384; i += 256){
    int arr = i >> 7, slot = i & 127;
    unsigned short* p = (arr == 0 ? qs2 : (arr == 1 ? ks2 : vt2));
    *(uint4*)(p + base + slot * 8) = z;
  }
}

// ---------------- tiled weight transpose: out[n][k] = bf16(in[k][n]) ----------------
__global__ __launch_bounds__(256) void wconv2_kernel(const float* __restrict__ in,
                                                     unsigned short* __restrict__ out,
                                                     int K, int N){
  __shared__ unsigned short t[32][33];
  int tx = threadIdx.x & 31, ty = threadIdx.x >> 5;
  int n0 = blockIdx.x * 32, k0 = blockIdx.y * 32;
  #pragma unroll
  for (int i = 0; i < 4; i++)
    t[ty + 8 * i][tx] = f2bf(in[(size_t)(k0 + ty + 8 * i) * N + n0 + tx]);
  __syncthreads();
  #pragma unroll
  for (int i = 0; i < 4; i++)
    out[(size_t)(n0 + ty + 8 * i) * K + k0 + tx] = t[tx][ty + 8 * i];
}

// ---------------- biasF prep: fragment-packed BF16 bias+mask, log2-domain ----------------
__global__ __launch_bounds__(256) void biasprep3_kernel(const float* __restrict__ rel,
                                                        unsigned short* __restrict__ biasF16){
  const int plane = blockIdx.y;            // cls*12+h
  const int cls = plane / 12, h = plane - cls * 12;
  const int qt = blockIdx.x / 11, t = blockIdx.x - qt * 11;
  const int tid = threadIdx.x;
  const int lane = tid >> 2, rb = (tid & 3) * 4;
  const int q = qt * 32 + (lane & 31);
  float v[4];
  #pragma unroll
  for (int j = 0; j < 4; j++){
    const int r = rb + j;
    const int mm = t * 32 + (r & 3) + 8 * (r >> 2) + 4 * (lane >> 5);
    float val;
    if (q >= 343 || mm >= 343) val = -1e30f;
    else {
      int qi0 = q / 49, qr = q - qi0 * 49, qi1 = qr / 7, qi2 = qr - qi1 * 7;
      int mi0 = mm / 49, mr = mm - mi0 * 49, mi1 = mr / 7, mi2 = mr - mi1 * 7;
      int idx = 13 * (qi0 - mi0 + 6) + (qi1 - mi1 + 6) + (qi2 - mi2);
      if (idx < 0) idx += 2197;
      val = rel[idx * 12 + h] * LOG2E;
      int az = (cls & 4) ? (qi0 < 4 ? 1 : 2) : 0;
      int ax = (cls & 2) ? (qi1 < 4 ? 1 : 2) : 0;
      int ay = (cls & 1) ? (qi2 < 4 ? 1 : 2) : 0;
      int bz = (cls & 4) ? (mi0 < 4 ? 1 : 2) : 0;
      int bx = (cls & 2) ? (mi1 < 4 ? 1 : 2) : 0;
      int by = (cls & 1) ? (mi2 < 4 ? 1 : 2) : 0;
      if (az * 9 + ax * 3 + ay != bz * 9 + bx * 3 + by) val += MASKC;
    }
    v[j] = val;
  }
  uint2 st;
  st.x = packbf(v[0], v[1]);
  st.y = packbf(v[2], v[3]);
  *(uint2*)(biasF16 + (((size_t)plane * 121 + blockIdx.x) * 64 + lane) * 16 + rb) = st;
}

// ---------------- LayerNorm (+optional shift+window-partition gather), vectorized ----------------
template<int MODE>
__global__ __launch_bounds__(256) void ln_kernel(const float* __restrict__ in,
                                                 const float* __restrict__ g,
                                                 const float* __restrict__ bta,
                                                 unsigned short* __restrict__ out){
  int wave = threadIdx.x >> 6, lane = threadIdx.x & 63;
  int row = blockIdx.x * 4 + wave;          // < 43904
  size_t srow;
  if (MODE == 0){
    int win = row / 343, n = row - win * 343;
    int b = win >> 6, w64 = win & 63;
    int zw = w64 >> 5, xw = (w64 >> 3) & 3, yw = w64 & 7;
    int i0 = n / 49, nr = n - i0 * 49, i1 = nr / 7, i2 = nr - i1 * 7;
    int zs = zw * 7 + i0 + 3; if (zs >= 14) zs -= 14;
    int xs = xw * 7 + i1 + 3; if (xs >= 28) xs -= 28;
    int ys = yw * 7 + i2 + 3; if (ys >= 56) ys -= 56;
    srow = (size_t)b * 21952 + zs * 1568 + xs * 56 + ys;
  } else {
    srow = (size_t)row;
  }
  const float* p = in + srow * 384;
  float v[6]; float s = 0.f;
  #pragma unroll
  for (int i = 0; i < 3; i++){
    f32x2 t = *(const f32x2*)(p + lane * 2 + i * 128);
    v[2 * i] = t[0]; v[2 * i + 1] = t[1];
    s += t[0] + t[1];
  }
  #pragma unroll
  for (int off = 32; off >= 1; off >>= 1) s += __shfl_xor(s, off);
  float mean = s * (1.f / 384.f);
  float vs = 0.f;
  #pragma unroll
  for (int i = 0; i < 6; i++){ float d = v[i] - mean; vs += d * d; }
  #pragma unroll
  for (int off = 32; off >= 1; off >>= 1) vs += __shfl_xor(vs, off);
  float rstd = rsqrtf(vs * (1.f / 384.f) + 1e-5f);
  unsigned short* o = out + (size_t)row * 384;
  #pragma unroll
  for (int i = 0; i < 3; i++){
    const int c = lane * 2 + i * 128;
    f32x2 gg = *(const f32x2*)(g + c);
    f32x2 bb = *(const f32x2*)(bta + c);
    float a0 = (v[2 * i] - mean) * rstd * gg[0] + bb[0];
    float a1 = (v[2 * i + 1] - mean) * rstd * gg[1] + bb[1];
    *(unsigned*)(&o[c]) = packbf(a0, a1);
  }
}

// ---------------- GEMM: C[M,N] = A[M,K] @ Bt[N,K]^T, operand-swapped MFMA, BK=64 ----------------
// r18 structure (best measured: BK=64, 16KB-LDS-x2, VGPR 64). BK=128 regressed (VGPR 140
// -> 1 block/CU, r20); BK=32 was slower (r5-r13). nt store only on EPI3 (full-line f32x4).
template<int EPI>
__global__ __launch_bounds__(256, 4) void gemm2(
    const unsigned short* __restrict__ A,
    const unsigned short* __restrict__ Bt,
    const float* __restrict__ bias,
    const float* __restrict__ resid,
    void* __restrict__ outp,
    unsigned short* __restrict__ oq,
    unsigned short* __restrict__ ok,
    unsigned short* __restrict__ ov,
    int K, int ldc, int nt_){
  __shared__ unsigned short As[8192];   // 16 KB: 2 ksub x 8 chunks x (16 rows x 32 k)
  __shared__ unsigned short Bs[8192];
  const int nwg = gridDim.x;
  const int qq = nwg >> 3, rr = nwg & 7;
  const int xcd = blockIdx.x & 7, pos = blockIdx.x >> 3;
  const int wgid = (xcd < rr ? xcd * (qq + 1) : rr * (qq + 1) + (xcd - rr) * qq) + pos;
  const int mtile = wgid / nt_, ntile = wgid - mtile * nt_;
  const int r0 = mtile * 128, c0 = ntile * 128;

  const int tid = threadIdx.x, lane = tid & 63, wave = tid >> 6;
  const int wr = (wave >> 1) * 64, wc = (wave & 1) * 64;
  f32x4 acc[4][4];
  #pragma unroll
  for (int mi = 0; mi < 4; mi++)
    #pragma unroll
    for (int ni = 0; ni < 4; ni++) acc[mi][ni] = f32x4{0.f, 0.f, 0.f, 0.f};

  const int srow = lane >> 2;
  const int koff = ((lane & 3) ^ ((lane >> 3) & 3)) * 8;
  const int kkey = (lane >> 1) & 3;

  for (int k0 = 0; k0 < K; k0 += 64){
    __syncthreads();
    #pragma unroll
    for (int i = 0; i < 8; i++){
      const int id = wave + i * 4;            // 0..31
      const int arr = id >> 4;                // 0=A, 1=B
      const int within = id & 15;
      const int ksub = within >> 3;           // 0,1
      const int sub = within & 7;             // 0..7
      const unsigned short* g = (arr ? Bt : A)
          + (size_t)((arr ? c0 : r0) + sub * 16 + srow) * K + k0 + ksub * 32 + koff;
      unsigned short* dst = (arr ? Bs : As) + ksub * 4096 + sub * 512;
      GLOAD16(g, dst);
    }
    __syncthreads();
    #pragma unroll
    for (int ks = 0; ks < 2; ks++){
      bf16x8 af[4], bfr[4];
      #pragma unroll
      for (int mi = 0; mi < 4; mi++)
        af[mi] = *(const bf16x8*)(&As[ks * 4096 + (wr + mi * 16 + (lane & 15)) * 32 + (((lane >> 4) ^ kkey) * 8)]);
      #pragma unroll
      for (int ni = 0; ni < 4; ni++)
        bfr[ni] = *(const bf16x8*)(&Bs[ks * 4096 + (wc + ni * 16 + (lane & 15)) * 32 + (((lane >> 4) ^ kkey) * 8)]);
      #pragma unroll
      for (int mi = 0; mi < 4; mi++)
        #pragma unroll
        for (int ni = 0; ni < 4; ni++)
          acc[mi][ni] = __builtin_amdgcn_mfma_f32_16x16x32_bf16(bfr[ni], af[mi], acc[mi][ni], 0, 0, 0);
    }
  }

  // ---- direct-from-acc epilogue: thread owns (row, 4 consecutive cols) per (mi,ni) ----
  const int lrow = lane & 15;
  const int cq4  = (lane >> 4) << 2;
  #pragma unroll
  for (int mi = 0; mi < 4; mi++){
    const int row = r0 + wr + mi * 16 + lrow;
    int win, m, t, mloc, vh2;
    size_t sdst;
    if (EPI == 0 || EPI == 1){ win = row / 343; m = row - win * 343; }
    if (EPI == 0){
      t = m >> 5; mloc = m & 31;
      vh2 = ((m >> 4) & 1) * 512 + ((m >> 3) & 1) * 256 + (m & 7);
    }
    if (EPI == 1){
      const int b = win >> 6, w64 = win & 63;
      const int zw = w64 >> 5, xw = (w64 >> 3) & 3, yw = w64 & 7;
      const int i0 = m / 49, nr = m - i0 * 49, i1 = nr / 7, i2 = nr - i1 * 7;
      int zf = zw * 7 + i0 + 3; if (zf >= 14) zf -= 14;
      int xf = xw * 7 + i1 + 3; if (xf >= 28) xf -= 28;
      int yf = yw * 7 + i2 + 3; if (yf >= 56) yf -= 56;
      sdst = ((size_t)b * 21952 + zf * 1568 + xf * 56 + yf) * 384;
    }
    #pragma unroll
    for (int ni = 0; ni < 4; ni++){
      const int colb = c0 + wc + ni * 16 + cq4;      // 4 consecutive cols
      float v[4];
      #pragma unroll
      for (int j = 0; j < 4; j++) v[j] = acc[mi][ni][j] + bias[colb + j];
      if (EPI == 2){
        #pragma unroll
        for (int j = 0; j < 4; j++)
          v[j] = v[j] * __builtin_amdgcn_rcpf(1.0f + exp2f(v[j] * -2.4554669f));
        uint2 st; st.x = packbf(v[0], v[1]); st.y = packbf(v[2], v[3]);
        *(uint2*)((unsigned short*)outp + (size_t)row * ldc + colb) = st;
      } else if (EPI == 3){
        const float* rsd = resid + (size_t)row * ldc + colb;
        f32x4 q = *(const f32x4*)rsd;
        f32x4 o4; o4[0] = v[0] + q[0]; o4[1] = v[1] + q[1];
        o4[2] = v[2] + q[2]; o4[3] = v[3] + q[3];
        __builtin_nontemporal_store(o4, (f32x4*)((float*)outp + (size_t)row * ldc + colb));
      } else if (EPI == 1){
        const float* rsd = resid + sdst + colb;
        f32x4 q = *(const f32x4*)rsd;
        f32x4 o4; o4[0] = v[0] + q[0]; o4[1] = v[1] + q[1];
        o4[2] = v[2] + q[2]; o4[3] = v[3] + q[3];
        *(f32x4*)((float*)outp + sdst + colb) = o4;
      } else { // EPI == 0
        if (c0 < 384){
          #pragma unroll
          for (int j = 0; j < 4; j++) v[j] *= SL2E;
          const int d = colb, h = d >> 5, dd = d & 31;
          const size_t off = (size_t)(win * 12 + h) * 11264
              + (size_t)(t * 1024 + ((dd >> 4) & 1) * 512 + ((dd >> 3) & 1) * 256 + mloc * 8 + (dd & 7));
          uint2 st; st.x = packbf(v[0], v[1]); st.y = packbf(v[2], v[3]);
          *(uint2*)(oq + off) = st;
        } else if (c0 < 768){
          const int d = colb - 384, h = d >> 5, dd = d & 31;
          const size_t off = (size_t)(win * 12 + h) * 11264
              + (size_t)(t * 1024 + ((dd >> 4) & 1) * 512 + ((dd >> 3) & 1) * 256 + mloc * 8 + (dd & 7));
          uint2 st; st.x = packbf(v[0], v[1]); st.y = packbf(v[2], v[3]);
          *(uint2*)(ok + off) = st;
        } else {
          const int d = colb - 768, h = d >> 5, dd = d & 31;
          const size_t off = (size_t)(win * 12 + h) * 11264 + (size_t)(t * 1024 + vh2);
          #pragma unroll
          for (int j = 0; j < 4; j++)
            ov[off + (size_t)(dd + j) * 8] = f2bf(v[j]);
        }
      }
    }
  }
}

// ---------------- MFMA attention v4: bf16 bias/mask unpacked as MFMA C-in; in-reg P ----
__global__ __launch_bounds__(256, 4) void attn4_kernel(
    const unsigned short* __restrict__ qs2,
    const unsigned short* __restrict__ ks2,
    const unsigned short* __restrict__ vt2,
    const unsigned short* __restrict__ biasF16,
    unsigned short* __restrict__ out){
  __shared__ unsigned short Ks[11264];     // 22 KB, chunk-packed
  const int wh = blockIdx.x;
  const int win = wh / 12, h = wh - win * 12;
  const int tid = threadIdx.x, wave = tid >> 6, lane = tid & 63;
  const int ln = lane & 31, hh = lane >> 5;

  const unsigned short* ksrc = ks2 + (size_t)wh * 11264;
  for (int c = wave; c < 22; c += 4)
    GLOAD16(ksrc + c * 512 + lane * 8, &Ks[c * 512]);

  const int w64 = win & 63;
  const int cls = (((w64 >> 5) & 1) ? 4 : 0) | ((((w64 >> 3) & 3) == 3) ? 2 : 0) | (((w64 & 7) == 7) ? 1 : 0);
  __syncthreads();

  const unsigned short* qbase = qs2 + (size_t)wh * 11264;
  const unsigned short* vbase = vt2 + (size_t)wh * 11264;
  const unsigned short* bbase = biasF16 + (size_t)(cls * 12 + h) * 123904 + lane * 16;

  for (int qt = wave; qt < 11; qt += 4){
    const bf16x8 bq0 = *(const bf16x8*)(qbase + qt * 1024 + hh * 256 + ln * 8);
    const bf16x8 bq1 = *(const bf16x8*)(qbase + qt * 1024 + 512 + hh * 256 + ln * 8);
    const unsigned short* brow = bbase + (size_t)qt * 11264;   // 11 tiles x 1024 ushort

    f32x16 o = zero16();
    float sum = 0.f;
    // prefetch t=0
    bf16x8 nbv0 = *(const bf16x8*)(vbase + hh * 256 + ln * 8);
    bf16x8 nbv1 = *(const bf16x8*)(vbase + 512 + hh * 256 + ln * 8);
    uint4 nbw0 = *(const uint4*)(brow);
    uint4 nbw1 = *(const uint4*)(brow + 8);

    for (int t = 0; t < 11; t++){
      const bf16x8 bv0 = nbv0, bv1 = nbv1;
      unsigned w[8];
      w[0] = nbw0.x; w[1] = nbw0.y; w[2] = nbw0.z; w[3] = nbw0.w;
      w[4] = nbw1.x; w[5] = nbw1.y; w[6] = nbw1.z; w[7] = nbw1.w;
      if (t < 10){
        const unsigned short* vnext = vbase + (t + 1) * 1024;
        nbv0 = *(const bf16x8*)(vnext + hh * 256 + ln * 8);
        nbv1 = *(const bf16x8*)(vnext + 512 + hh * 256 + ln * 8);
        nbw0 = *(const uint4*)(brow + (t + 1) * 1024);
        nbw1 = *(const uint4*)(brow + (t + 1) * 1024 + 8);
      }
      f32x16 acc;                            // C-in = bias + mask (log2-domain), bf16-unpacked
      #pragma unroll
      for (int j = 0; j < 8; j++){
        acc[2 * j]     = __uint_as_float(w[j] << 16);
        acc[2 * j + 1] = __uint_as_float(w[j] & 0xffff0000u);
      }
      const bf16x8 ka0 = *(const bf16x8*)(&Ks[t * 1024 + hh * 256 + ln * 8]);
      const bf16x8 ka1 = *(const bf16x8*)(&Ks[t * 1024 + 512 + hh * 256 + ln * 8]);
      acc = __builtin_amdgcn_mfma_f32_32x32x16_bf16(ka0, bq0, acc, 0, 0, 0);
      acc = __builtin_amdgcn_mfma_f32_32x32x16_bf16(ka1, bq1, acc, 0, 0, 0);

      float pv[16];
      #pragma unroll
      for (int r = 0; r < 16; r++){
        const float e = exp2f(acc[r]);
        sum += e;
        pv[r] = e;
      }
      // in-register P -> A-frag via cvt_pk + permlane32_swap (T12)
      unsigned a0 = packbf(pv[0], pv[1]),  b0 = packbf(pv[4], pv[5]);
      unsigned a1 = packbf(pv[2], pv[3]),  b1 = packbf(pv[6], pv[7]);
      unsigned a2 = packbf(pv[8], pv[9]),  b2 = packbf(pv[12], pv[13]);
      unsigned a3 = packbf(pv[10], pv[11]), b3 = packbf(pv[14], pv[15]);
      asm volatile("v_permlane32_swap_b32 %0, %1" : "+v"(a0), "+v"(b0));
      asm volatile("v_permlane32_swap_b32 %0, %1" : "+v"(a1), "+v"(b1));
      asm volatile("v_permlane32_swap_b32 %0, %1" : "+v"(a2), "+v"(b2));
      asm volatile("v_permlane32_swap_b32 %0, %1" : "+v"(a3), "+v"(b3));
      union { unsigned u[4]; bf16x8 v; } p0c, p1c;
      p0c.u[0] = a0; p0c.u[1] = a1; p0c.u[2] = b0; p0c.u[3] = b1;
      p1c.u[0] = a2; p1c.u[1] = a3; p1c.u[2] = b2; p1c.u[3] = b3;
      o = __builtin_amdgcn_mfma_f32_32x32x16_bf16(p0c.v, bv0, o, 0, 0, 0);
      o = __builtin_amdgcn_mfma_f32_32x32x16_bf16(p1c.v, bv1, o, 0, 0, 0);
    }
    sum += __shfl_xor(sum, 32);
    const float inv = 1.f / sum;   // lane ln holds inv for q-local = ln
    #pragma unroll
    for (int r = 0; r < 16; r++){
      const int qloc = (r & 3) + 8 * (r >> 2) + 4 * hh;
      const float iv = __shfl(inv, qloc);
      const int qg = qt * 32 + qloc;
      if (qg < 343)
        out[((size_t)win * 343 + qg) * 384 + h * 32 + ln] = f2bf(o[r] * iv);
    }
  }
}

// ---------------- host launcher ----------------
extern "C" void kernel_launch(void* const* d_in, const int* in_sizes, int n_in,
                              void* d_out, int out_size, void* d_ws, size_t ws_size,
                              hipStream_t stream){
  const float* x      = (const float*)d_in[0];
  const float* n1g    = (const float*)d_in[1];
  const float* n1b    = (const float*)d_in[2];
  const float* qkv_w  = (const float*)d_in[3];
  const float* qkv_b  = (const float*)d_in[4];
  const float* proj_w = (const float*)d_in[5];
  const float* proj_b = (const float*)d_in[6];
  const float* rel    = (const float*)d_in[7];
  const float* n2g    = (const float*)d_in[8];
  const float* n2b    = (const float*)d_in[9];
  const float* fc1_w  = (const float*)d_in[10];
  const float* fc1_b  = (const float*)d_in[11];
  const float* fc2_w  = (const float*)d_in[12];
  const float* fc2_b  = (const float*)d_in[13];
  float* out = (float*)d_out;

  char* ws = (char*)d_ws;
  // Region plan (bytes), high-water 239,566,848:
  // [0, 33.7M)            w_win bf16 [43904][384]      -- reused as hidden bf16 (0..134.9M)
  // [33.7M, 68.3M)        qs2 ; [68.3M, 102.9M) ks2 ; [102.9M, 137.5M) vt2   -- dead after attn
  // [134.9M, 202.3M)      x2 f32 (written post-attn); pre-attn holds biasF16 @137.5M (23.8MB)
  // [202.3M, 236.0M)      att bf16 -- reused as ln2
  // [236.0M, 239.6M)      bf16 transposed weights
  // All attn-read regions (incl. pads) rewritten EVERY call.
  unsigned short* w_win  = (unsigned short*)(ws + 0);
  unsigned short* hidden = (unsigned short*)(ws + 0);
  unsigned short* qs2    = (unsigned short*)(ws + 33718272ull);
  unsigned short* ks2    = (unsigned short*)(ws + 68321280ull);
  unsigned short* vt2    = (unsigned short*)(ws + 102924288ull);
  float*          x2     = (float*)(ws + 134873088ull);
  unsigned short* biasF16= (unsigned short*)(ws + 137527296ull);  // 23,789,568 B
  unsigned short* att    = (unsigned short*)(ws + 202309632ull);
  unsigned short* ln2    = att;
  unsigned short* wt_qkv = (unsigned short*)(ws + 236027904ull);
  unsigned short* wt_prj = (unsigned short*)(ws + 236912640ull);
  unsigned short* wt_fc1 = (unsigned short*)(ws + 237207552ull);
  unsigned short* wt_fc2 = (unsigned short*)(ws + 238387200ull);

  wconv2_kernel<<<dim3(36, 12), 256, 0, stream>>>(qkv_w, wt_qkv, 384, 1152);
  wconv2_kernel<<<dim3(12, 12), 256, 0, stream>>>(proj_w, wt_prj, 384, 384);
  wconv2_kernel<<<dim3(48, 12), 256, 0, stream>>>(fc1_w, wt_fc1, 384, 1536);
  wconv2_kernel<<<dim3(12, 48), 256, 0, stream>>>(fc2_w, wt_fc2, 1536, 384);
  biasprep3_kernel<<<dim3(121, 96), 256, 0, stream>>>(rel, biasF16);
  padzero_kernel<<<1536, 256, 0, stream>>>(qs2, ks2, vt2);

  ln_kernel<0><<<10976, 256, 0, stream>>>(x, n1g, n1b, w_win);
  gemm2<0><<<343 * 9, 256, 0, stream>>>(w_win, wt_qkv, qkv_b, nullptr, nullptr,
                                        qs2, ks2, vt2, 384, 0, 9);
  attn4_kernel<<<1536, 256, 0, stream>>>(qs2, ks2, vt2, biasF16, att);
  gemm2<1><<<343 * 3, 256, 0, stream>>>(att, wt_prj, proj_b, x, x2,
                                        nullptr, nullptr, nullptr, 384, 384, 3);
  ln_kernel<1><<<10976, 256, 0, stream>>>(x2, n2g, n2b, ln2);
  gemm2<2><<<343 * 12, 256, 0, stream>>>(ln2, wt_fc1, fc1_b, nullptr, hidden,
                                         nullptr, nullptr, nullptr, 384, 1536, 12);
  gemm2<3><<<343 * 3, 256, 0, stream>>>(hidden, wt_fc2, fc2_b, x2, out,
                                        nullptr, nullptr, nullptr, 1536, 384, 3);
}

// Round 22
// 430.612 us; speedup vs baseline: 1.2082x; 1.0367x over previous
//
#include <hip/hip_runtime.h>
#include <hip/hip_bf16.h>
#include <cmath>

typedef float f32x2 __attribute__((ext_vector_type(2)));
typedef float f32x4 __attribute__((ext_vector_type(4)));
typedef float f32x16 __attribute__((ext_vector_type(16)));
typedef short bf16x8 __attribute__((ext_vector_type(8)));
typedef const __attribute__((address_space(1))) unsigned int* gas_t;
typedef __attribute__((address_space(3))) unsigned int* las_t;

#define GLOAD16(g, l) __builtin_amdgcn_global_load_lds((gas_t)(const void*)(g), (las_t)(void*)(l), 16, 0, 0)

#define LOG2E 1.4426950408889634f
#define MASKC (-144.2695040888963f)
#define SL2E  (0.17677669529663687f * 1.4426950408889634f)

static __device__ __forceinline__ float bf2f(unsigned short u){
  return __uint_as_float(((unsigned)u) << 16);
}
static __device__ __forceinline__ unsigned short f2bf(float f){
  unsigned u = __float_as_uint(f);
  unsigned r = u + 0x7FFFu + ((u >> 16) & 1u);
  return (unsigned short)(r >> 16);
}
static __device__ __forceinline__ unsigned packbf(float a, float b){
  union { __hip_bfloat162 h; unsigned u; } cv;
  cv.h = __float22bfloat162_rn(make_float2(a, b));
  return cv.u;
}
static __device__ __forceinline__ f32x16 zero16(){
  f32x16 z;
  #pragma unroll
  for (int i = 0; i < 16; i++) z[i] = 0.f;
  return z;
}

// ---------------- merged prep: weight transposes + bias table + pad zeroing ----------------
static __device__ __forceinline__ void wconv_body(const float* __restrict__ in,
                                                  unsigned short* __restrict__ out,
                                                  int K, int N, int bx, int by,
                                                  unsigned short (*t)[33]){
  const int tx = threadIdx.x & 31, ty = threadIdx.x >> 5;
  const int n0 = bx * 32, k0 = by * 32;
  #pragma unroll
  for (int i = 0; i < 4; i++)
    t[ty + 8 * i][tx] = f2bf(in[(size_t)(k0 + ty + 8 * i) * N + n0 + tx]);
  __syncthreads();
  #pragma unroll
  for (int i = 0; i < 4; i++)
    out[(size_t)(n0 + ty + 8 * i) * K + k0 + tx] = t[tx][ty + 8 * i];
}

static __device__ __forceinline__ void biasprep_body(const float* __restrict__ rel,
                                                     unsigned short* __restrict__ biasF16,
                                                     int bx, int plane){
  const int cls = plane / 12, h = plane - cls * 12;
  const int tid = threadIdx.x;
  const int lane = tid >> 2, rb = (tid & 3) * 4;
  const int qt = bx / 11, t = bx - qt * 11;
  const int q = qt * 32 + (lane & 31);
  float v[4];
  #pragma unroll
  for (int j = 0; j < 4; j++){
    const int r = rb + j;
    const int mm = t * 32 + (r & 3) + 8 * (r >> 2) + 4 * (lane >> 5);
    float val;
    if (q >= 343 || mm >= 343) val = -1e30f;
    else {
      int qi0 = q / 49, qr = q - qi0 * 49, qi1 = qr / 7, qi2 = qr - qi1 * 7;
      int mi0 = mm / 49, mr = mm - mi0 * 49, mi1 = mr / 7, mi2 = mr - mi1 * 7;
      int idx = 13 * (qi0 - mi0 + 6) + (qi1 - mi1 + 6) + (qi2 - mi2);
      if (idx < 0) idx += 2197;
      val = rel[idx * 12 + h] * LOG2E;
      int az = (cls & 4) ? (qi0 < 4 ? 1 : 2) : 0;
      int ax = (cls & 2) ? (qi1 < 4 ? 1 : 2) : 0;
      int ay = (cls & 1) ? (qi2 < 4 ? 1 : 2) : 0;
      int bz = (cls & 4) ? (mi0 < 4 ? 1 : 2) : 0;
      int bxm = (cls & 2) ? (mi1 < 4 ? 1 : 2) : 0;
      int by = (cls & 1) ? (mi2 < 4 ? 1 : 2) : 0;
      if (az * 9 + ax * 3 + ay != bz * 9 + bxm * 3 + by) val += MASKC;
    }
    v[j] = val;
  }
  uint2 st;
  st.x = packbf(v[0], v[1]);
  st.y = packbf(v[2], v[3]);
  *(uint2*)(biasF16 + (((size_t)plane * 121 + bx) * 64 + lane) * 16 + rb) = st;
}

static __device__ __forceinline__ void padzero_body(unsigned short* __restrict__ qs2,
                                                    unsigned short* __restrict__ ks2,
                                                    unsigned short* __restrict__ vt2,
                                                    int wh){
  uint4 z = make_uint4(0, 0, 0, 0);
  const size_t base = (size_t)wh * 11264 + 10 * 1024;
  for (int i = threadIdx.x; i < 384; i += 256){
    int arr = i >> 7, slot = i & 127;
    unsigned short* p = (arr == 0 ? qs2 : (arr == 1 ? ks2 : vt2));
    *(uint4*)(p + base + slot * 8) = z;
  }
}

// one launch replaces 6: [0,432) wconv qkv | [432,576) wconv proj | [576,1152) wconv fc1
// | [1152,1728) wconv fc2 | [1728,13344) biasprep | [13344,14880) padzero
__global__ __launch_bounds__(256) void prep_kernel(
    const float* __restrict__ qkv_w, const float* __restrict__ proj_w,
    const float* __restrict__ fc1_w, const float* __restrict__ fc2_w,
    const float* __restrict__ rel,
    unsigned short* __restrict__ wt_qkv, unsigned short* __restrict__ wt_prj,
    unsigned short* __restrict__ wt_fc1, unsigned short* __restrict__ wt_fc2,
    unsigned short* __restrict__ biasF16,
    unsigned short* __restrict__ qs2, unsigned short* __restrict__ ks2,
    unsigned short* __restrict__ vt2){
  __shared__ unsigned short t[32][33];
  int id = blockIdx.x;
  if (id < 432){ wconv_body(qkv_w, wt_qkv, 384, 1152, id % 36, id / 36, t); return; }
  id -= 432;
  if (id < 144){ wconv_body(proj_w, wt_prj, 384, 384, id % 12, id / 12, t); return; }
  id -= 144;
  if (id < 576){ wconv_body(fc1_w, wt_fc1, 384, 1536, id % 48, id / 48, t); return; }
  id -= 576;
  if (id < 576){ wconv_body(fc2_w, wt_fc2, 1536, 384, id % 12, id / 12, t); return; }
  id -= 576;
  if (id < 11616){ biasprep_body(rel, biasF16, id % 121, id / 121); return; }
  id -= 11616;
  padzero_body(qs2, ks2, vt2, id);
}

// ---------------- LayerNorm (+optional shift+window-partition gather), vectorized ----------------
template<int MODE>
__global__ __launch_bounds__(256) void ln_kernel(const float* __restrict__ in,
                                                 const float* __restrict__ g,
                                                 const float* __restrict__ bta,
                                                 unsigned short* __restrict__ out){
  int wave = threadIdx.x >> 6, lane = threadIdx.x & 63;
  int row = blockIdx.x * 4 + wave;          // < 43904
  size_t srow;
  if (MODE == 0){
    int win = row / 343, n = row - win * 343;
    int b = win >> 6, w64 = win & 63;
    int zw = w64 >> 5, xw = (w64 >> 3) & 3, yw = w64 & 7;
    int i0 = n / 49, nr = n - i0 * 49, i1 = nr / 7, i2 = nr - i1 * 7;
    int zs = zw * 7 + i0 + 3; if (zs >= 14) zs -= 14;
    int xs = xw * 7 + i1 + 3; if (xs >= 28) xs -= 28;
    int ys = yw * 7 + i2 + 3; if (ys >= 56) ys -= 56;
    srow = (size_t)b * 21952 + zs * 1568 + xs * 56 + ys;
  } else {
    srow = (size_t)row;
  }
  const float* p = in + srow * 384;
  float v[6]; float s = 0.f;
  #pragma unroll
  for (int i = 0; i < 3; i++){
    f32x2 t = *(const f32x2*)(p + lane * 2 + i * 128);
    v[2 * i] = t[0]; v[2 * i + 1] = t[1];
    s += t[0] + t[1];
  }
  #pragma unroll
  for (int off = 32; off >= 1; off >>= 1) s += __shfl_xor(s, off);
  float mean = s * (1.f / 384.f);
  float vs = 0.f;
  #pragma unroll
  for (int i = 0; i < 6; i++){ float d = v[i] - mean; vs += d * d; }
  #pragma unroll
  for (int off = 32; off >= 1; off >>= 1) vs += __shfl_xor(vs, off);
  float rstd = rsqrtf(vs * (1.f / 384.f) + 1e-5f);
  unsigned short* o = out + (size_t)row * 384;
  #pragma unroll
  for (int i = 0; i < 3; i++){
    const int c = lane * 2 + i * 128;
    f32x2 gg = *(const f32x2*)(g + c);
    f32x2 bb = *(const f32x2*)(bta + c);
    float a0 = (v[2 * i] - mean) * rstd * gg[0] + bb[0];
    float a1 = (v[2 * i + 1] - mean) * rstd * gg[1] + bb[1];
    *(unsigned*)(&o[c]) = packbf(a0, a1);
  }
}

// ---------------- GEMM: C[M,N] = A[M,K] @ Bt[N,K]^T, operand-swapped MFMA, BK=64 ----------------
// r18 structure (best measured: BK=64, 16KB-LDS-x2, VGPR 64). BK=128 regressed (VGPR 140
// -> 1 block/CU, r20); BK=32 was slower (r5-r13). nt store only on EPI3 (full-line f32x4).
template<int EPI>
__global__ __launch_bounds__(256, 4) void gemm2(
    const unsigned short* __restrict__ A,
    const unsigned short* __restrict__ Bt,
    const float* __restrict__ bias,
    const float* __restrict__ resid,
    void* __restrict__ outp,
    unsigned short* __restrict__ oq,
    unsigned short* __restrict__ ok,
    unsigned short* __restrict__ ov,
    int K, int ldc, int nt_){
  __shared__ unsigned short As[8192];   // 16 KB: 2 ksub x 8 chunks x (16 rows x 32 k)
  __shared__ unsigned short Bs[8192];
  const int nwg = gridDim.x;
  const int qq = nwg >> 3, rr = nwg & 7;
  const int xcd = blockIdx.x & 7, pos = blockIdx.x >> 3;
  const int wgid = (xcd < rr ? xcd * (qq + 1) : rr * (qq + 1) + (xcd - rr) * qq) + pos;
  const int mtile = wgid / nt_, ntile = wgid - mtile * nt_;
  const int r0 = mtile * 128, c0 = ntile * 128;

  const int tid = threadIdx.x, lane = tid & 63, wave = tid >> 6;
  const int wr = (wave >> 1) * 64, wc = (wave & 1) * 64;
  f32x4 acc[4][4];
  #pragma unroll
  for (int mi = 0; mi < 4; mi++)
    #pragma unroll
    for (int ni = 0; ni < 4; ni++) acc[mi][ni] = f32x4{0.f, 0.f, 0.f, 0.f};

  const int srow = lane >> 2;
  const int koff = ((lane & 3) ^ ((lane >> 3) & 3)) * 8;
  const int kkey = (lane >> 1) & 3;

  for (int k0 = 0; k0 < K; k0 += 64){
    __syncthreads();
    #pragma unroll
    for (int i = 0; i < 8; i++){
      const int id = wave + i * 4;            // 0..31
      const int arr = id >> 4;                // 0=A, 1=B
      const int within = id & 15;
      const int ksub = within >> 3;           // 0,1
      const int sub = within & 7;             // 0..7
      const unsigned short* g = (arr ? Bt : A)
          + (size_t)((arr ? c0 : r0) + sub * 16 + srow) * K + k0 + ksub * 32 + koff;
      unsigned short* dst = (arr ? Bs : As) + ksub * 4096 + sub * 512;
      GLOAD16(g, dst);
    }
    __syncthreads();
    #pragma unroll
    for (int ks = 0; ks < 2; ks++){
      bf16x8 af[4], bfr[4];
      #pragma unroll
      for (int mi = 0; mi < 4; mi++)
        af[mi] = *(const bf16x8*)(&As[ks * 4096 + (wr + mi * 16 + (lane & 15)) * 32 + (((lane >> 4) ^ kkey) * 8)]);
      #pragma unroll
      for (int ni = 0; ni < 4; ni++)
        bfr[ni] = *(const bf16x8*)(&Bs[ks * 4096 + (wc + ni * 16 + (lane & 15)) * 32 + (((lane >> 4) ^ kkey) * 8)]);
      #pragma unroll
      for (int mi = 0; mi < 4; mi++)
        #pragma unroll
        for (int ni = 0; ni < 4; ni++)
          acc[mi][ni] = __builtin_amdgcn_mfma_f32_16x16x32_bf16(bfr[ni], af[mi], acc[mi][ni], 0, 0, 0);
    }
  }

  // ---- direct-from-acc epilogue: thread owns (row, 4 consecutive cols) per (mi,ni) ----
  const int lrow = lane & 15;
  const int cq4  = (lane >> 4) << 2;
  #pragma unroll
  for (int mi = 0; mi < 4; mi++){
    const int row = r0 + wr + mi * 16 + lrow;
    int win, m, t, mloc, vh2;
    size_t sdst;
    if (EPI == 0 || EPI == 1){ win = row / 343; m = row - win * 343; }
    if (EPI == 0){
      t = m >> 5; mloc = m & 31;
      vh2 = ((m >> 4) & 1) * 512 + ((m >> 3) & 1) * 256 + (m & 7);
    }
    if (EPI == 1){
      const int b = win >> 6, w64 = win & 63;
      const int zw = w64 >> 5, xw = (w64 >> 3) & 3, yw = w64 & 7;
      const int i0 = m / 49, nr = m - i0 * 49, i1 = nr / 7, i2 = nr - i1 * 7;
      int zf = zw * 7 + i0 + 3; if (zf >= 14) zf -= 14;
      int xf = xw * 7 + i1 + 3; if (xf >= 28) xf -= 28;
      int yf = yw * 7 + i2 + 3; if (yf >= 56) yf -= 56;
      sdst = ((size_t)b * 21952 + zf * 1568 + xf * 56 + yf) * 384;
    }
    #pragma unroll
    for (int ni = 0; ni < 4; ni++){
      const int colb = c0 + wc + ni * 16 + cq4;      // 4 consecutive cols
      float v[4];
      #pragma unroll
      for (int j = 0; j < 4; j++) v[j] = acc[mi][ni][j] + bias[colb + j];
      if (EPI == 2){
        #pragma unroll
        for (int j = 0; j < 4; j++)
          v[j] = v[j] * __builtin_amdgcn_rcpf(1.0f + exp2f(v[j] * -2.4554669f));
        uint2 st; st.x = packbf(v[0], v[1]); st.y = packbf(v[2], v[3]);
        *(uint2*)((unsigned short*)outp + (size_t)row * ldc + colb) = st;
      } else if (EPI == 3){
        const float* rsd = resid + (size_t)row * ldc + colb;
        f32x4 q = *(const f32x4*)rsd;
        f32x4 o4; o4[0] = v[0] + q[0]; o4[1] = v[1] + q[1];
        o4[2] = v[2] + q[2]; o4[3] = v[3] + q[3];
        __builtin_nontemporal_store(o4, (f32x4*)((float*)outp + (size_t)row * ldc + colb));
      } else if (EPI == 1){
        const float* rsd = resid + sdst + colb;
        f32x4 q = *(const f32x4*)rsd;
        f32x4 o4; o4[0] = v[0] + q[0]; o4[1] = v[1] + q[1];
        o4[2] = v[2] + q[2]; o4[3] = v[3] + q[3];
        *(f32x4*)((float*)outp + sdst + colb) = o4;
      } else { // EPI == 0
        if (c0 < 384){
          #pragma unroll
          for (int j = 0; j < 4; j++) v[j] *= SL2E;
          const int d = colb, h = d >> 5, dd = d & 31;
          const size_t off = (size_t)(win * 12 + h) * 11264
              + (size_t)(t * 1024 + ((dd >> 4) & 1) * 512 + ((dd >> 3) & 1) * 256 + mloc * 8 + (dd & 7));
          uint2 st; st.x = packbf(v[0], v[1]); st.y = packbf(v[2], v[3]);
          *(uint2*)(oq + off) = st;
        } else if (c0 < 768){
          const int d = colb - 384, h = d >> 5, dd = d & 31;
          const size_t off = (size_t)(win * 12 + h) * 11264
              + (size_t)(t * 1024 + ((dd >> 4) & 1) * 512 + ((dd >> 3) & 1) * 256 + mloc * 8 + (dd & 7));
          uint2 st; st.x = packbf(v[0], v[1]); st.y = packbf(v[2], v[3]);
          *(uint2*)(ok + off) = st;
        } else {
          const int d = colb - 768, h = d >> 5, dd = d & 31;
          const size_t off = (size_t)(win * 12 + h) * 11264 + (size_t)(t * 1024 + vh2);
          #pragma unroll
          for (int j = 0; j < 4; j++)
            ov[off + (size_t)(dd + j) * 8] = f2bf(v[j]);
        }
      }
    }
  }
}

// ---------------- MFMA attention v4: bf16 bias/mask unpacked as MFMA C-in; in-reg P ----
__global__ __launch_bounds__(256, 4) void attn4_kernel(
    const unsigned short* __restrict__ qs2,
    const unsigned short* __restrict__ ks2,
    const unsigned short* __restrict__ vt2,
    const unsigned short* __restrict__ biasF16,
    unsigned short* __restrict__ out){
  __shared__ unsigned short Ks[11264];     // 22 KB, chunk-packed
  const int wh = blockIdx.x;
  const int win = wh / 12, h = wh - win * 12;
  const int tid = threadIdx.x, wave = tid >> 6, lane = tid & 63;
  const int ln = lane & 31, hh = lane >> 5;

  const unsigned short* ksrc = ks2 + (size_t)wh * 11264;
  for (int c = wave; c < 22; c += 4)
    GLOAD16(ksrc + c * 512 + lane * 8, &Ks[c * 512]);

  const int w64 = win & 63;
  const int cls = (((w64 >> 5) & 1) ? 4 : 0) | ((((w64 >> 3) & 3) == 3) ? 2 : 0) | (((w64 & 7) == 7) ? 1 : 0);
  __syncthreads();

  const unsigned short* qbase = qs2 + (size_t)wh * 11264;
  const unsigned short* vbase = vt2 + (size_t)wh * 11264;
  const unsigned short* bbase = biasF16 + (size_t)(cls * 12 + h) * 123904 + lane * 16;

  for (int qt = wave; qt < 11; qt += 4){
    const bf16x8 bq0 = *(const bf16x8*)(qbase + qt * 1024 + hh * 256 + ln * 8);
    const bf16x8 bq1 = *(const bf16x8*)(qbase + qt * 1024 + 512 + hh * 256 + ln * 8);
    const unsigned short* brow = bbase + (size_t)qt * 11264;   // 11 tiles x 1024 ushort

    f32x16 o = zero16();
    float sum = 0.f;
    // prefetch t=0
    bf16x8 nbv0 = *(const bf16x8*)(vbase + hh * 256 + ln * 8);
    bf16x8 nbv1 = *(const bf16x8*)(vbase + 512 + hh * 256 + ln * 8);
    uint4 nbw0 = *(const uint4*)(brow);
    uint4 nbw1 = *(const uint4*)(brow + 8);

    for (int t = 0; t < 11; t++){
      const bf16x8 bv0 = nbv0, bv1 = nbv1;
      unsigned w[8];
      w[0] = nbw0.x; w[1] = nbw0.y; w[2] = nbw0.z; w[3] = nbw0.w;
      w[4] = nbw1.x; w[5] = nbw1.y; w[6] = nbw1.z; w[7] = nbw1.w;
      if (t < 10){
        const unsigned short* vnext = vbase + (t + 1) * 1024;
        nbv0 = *(const bf16x8*)(vnext + hh * 256 + ln * 8);
        nbv1 = *(const bf16x8*)(vnext + 512 + hh * 256 + ln * 8);
        nbw0 = *(const uint4*)(brow + (t + 1) * 1024);
        nbw1 = *(const uint4*)(brow + (t + 1) * 1024 + 8);
      }
      f32x16 acc;                            // C-in = bias + mask (log2-domain), bf16-unpacked
      #pragma unroll
      for (int j = 0; j < 8; j++){
        acc[2 * j]     = __uint_as_float(w[j] << 16);
        acc[2 * j + 1] = __uint_as_float(w[j] & 0xffff0000u);
      }
      const bf16x8 ka0 = *(const bf16x8*)(&Ks[t * 1024 + hh * 256 + ln * 8]);
      const bf16x8 ka1 = *(const bf16x8*)(&Ks[t * 1024 + 512 + hh * 256 + ln * 8]);
      acc = __builtin_amdgcn_mfma_f32_32x32x16_bf16(ka0, bq0, acc, 0, 0, 0);
      acc = __builtin_amdgcn_mfma_f32_32x32x16_bf16(ka1, bq1, acc, 0, 0, 0);

      float pv[16];
      #pragma unroll
      for (int r = 0; r < 16; r++){
        const float e = exp2f(acc[r]);
        sum += e;
        pv[r] = e;
      }
      // in-register P -> A-frag via cvt_pk + permlane32_swap (T12)
      unsigned a0 = packbf(pv[0], pv[1]),  b0 = packbf(pv[4], pv[5]);
      unsigned a1 = packbf(pv[2], pv[3]),  b1 = packbf(pv[6], pv[7]);
      unsigned a2 = packbf(pv[8], pv[9]),  b2 = packbf(pv[12], pv[13]);
      unsigned a3 = packbf(pv[10], pv[11]), b3 = packbf(pv[14], pv[15]);
      asm volatile("v_permlane32_swap_b32 %0, %1" : "+v"(a0), "+v"(b0));
      asm volatile("v_permlane32_swap_b32 %0, %1" : "+v"(a1), "+v"(b1));
      asm volatile("v_permlane32_swap_b32 %0, %1" : "+v"(a2), "+v"(b2));
      asm volatile("v_permlane32_swap_b32 %0, %1" : "+v"(a3), "+v"(b3));
      union { unsigned u[4]; bf16x8 v; } p0c, p1c;
      p0c.u[0] = a0; p0c.u[1] = a1; p0c.u[2] = b0; p0c.u[3] = b1;
      p1c.u[0] = a2; p1c.u[1] = a3; p1c.u[2] = b2; p1c.u[3] = b3;
      o = __builtin_amdgcn_mfma_f32_32x32x16_bf16(p0c.v, bv0, o, 0, 0, 0);
      o = __builtin_amdgcn_mfma_f32_32x32x16_bf16(p1c.v, bv1, o, 0, 0, 0);
    }
    sum += __shfl_xor(sum, 32);
    const float inv = 1.f / sum;   // lane ln holds inv for q-local = ln
    #pragma unroll
    for (int r = 0; r < 16; r++){
      const int qloc = (r & 3) + 8 * (r >> 2) + 4 * hh;
      const float iv = __shfl(inv, qloc);
      const int qg = qt * 32 + qloc;
      if (qg < 343)
        out[((size_t)win * 343 + qg) * 384 + h * 32 + ln] = f2bf(o[r] * iv);
    }
  }
}

// ---------------- host launcher ----------------
extern "C" void kernel_launch(void* const* d_in, const int* in_sizes, int n_in,
                              void* d_out, int out_size, void* d_ws, size_t ws_size,
                              hipStream_t stream){
  const float* x      = (const float*)d_in[0];
  const float* n1g    = (const float*)d_in[1];
  const float* n1b    = (const float*)d_in[2];
  const float* qkv_w  = (const float*)d_in[3];
  const float* qkv_b  = (const float*)d_in[4];
  const float* proj_w = (const float*)d_in[5];
  const float* proj_b = (const float*)d_in[6];
  const float* rel    = (const float*)d_in[7];
  const float* n2g    = (const float*)d_in[8];
  const float* n2b    = (const float*)d_in[9];
  const float* fc1_w  = (const float*)d_in[10];
  const float* fc1_b  = (const float*)d_in[11];
  const float* fc2_w  = (const float*)d_in[12];
  const float* fc2_b  = (const float*)d_in[13];
  float* out = (float*)d_out;

  char* ws = (char*)d_ws;
  // Region plan (bytes), high-water 239,566,848:
  // [0, 33.7M)            w_win bf16 [43904][384]      -- reused as hidden bf16 (0..134.9M)
  // [33.7M, 68.3M)        qs2 ; [68.3M, 102.9M) ks2 ; [102.9M, 137.5M) vt2   -- dead after attn
  // [134.9M, 202.3M)      x2 f32 (written post-attn); pre-attn holds biasF16 @137.5M (23.8MB)
  // [202.3M, 236.0M)      att bf16 -- reused as ln2
  // [236.0M, 239.6M)      bf16 transposed weights
  // All attn-read regions (incl. pads) rewritten EVERY call.
  unsigned short* w_win  = (unsigned short*)(ws + 0);
  unsigned short* hidden = (unsigned short*)(ws + 0);
  unsigned short* qs2    = (unsigned short*)(ws + 33718272ull);
  unsigned short* ks2    = (unsigned short*)(ws + 68321280ull);
  unsigned short* vt2    = (unsigned short*)(ws + 102924288ull);
  float*          x2     = (float*)(ws + 134873088ull);
  unsigned short* biasF16= (unsigned short*)(ws + 137527296ull);  // 23,789,568 B
  unsigned short* att    = (unsigned short*)(ws + 202309632ull);
  unsigned short* ln2    = att;
  unsigned short* wt_qkv = (unsigned short*)(ws + 236027904ull);
  unsigned short* wt_prj = (unsigned short*)(ws + 236912640ull);
  unsigned short* wt_fc1 = (unsigned short*)(ws + 237207552ull);
  unsigned short* wt_fc2 = (unsigned short*)(ws + 238387200ull);

  prep_kernel<<<14880, 256, 0, stream>>>(qkv_w, proj_w, fc1_w, fc2_w, rel,
                                         wt_qkv, wt_prj, wt_fc1, wt_fc2, biasF16,
                                         qs2, ks2, vt2);

  ln_kernel<0><<<10976, 256, 0, stream>>>(x, n1g, n1b, w_win);
  gemm2<0><<<343 * 9, 256, 0, stream>>>(w_win, wt_qkv, qkv_b, nullptr, nullptr,
                                        qs2, ks2, vt2, 384, 0, 9);
  attn4_kernel<<<1536, 256, 0, stream>>>(qs2, ks2, vt2, biasF16, att);
  gemm2<1><<<343 * 3, 256, 0, stream>>>(att, wt_prj, proj_b, x, x2,
                                        nullptr, nullptr, nullptr, 384, 384, 3);
  ln_kernel<1><<<10976, 256, 0, stream>>>(x2, n2g, n2b, ln2);
  gemm2<2><<<343 * 12, 256, 0, stream>>>(ln2, wt_fc1, fc1_b, nullptr, hidden,
                                         nullptr, nullptr, nullptr, 384, 1536, 12);
  gemm2<3><<<343 * 3, 256, 0, stream>>>(hidden, wt_fc2, fc2_b, x2, out,
                                        nullptr, nullptr, nullptr, 1536, 384, 3);
}

// Round 23
// 427.138 us; speedup vs baseline: 1.2180x; 1.0081x over previous
//
#include <hip/hip_runtime.h>
#include <hip/hip_bf16.h>
#include <cmath>

typedef float f32x2 __attribute__((ext_vector_type(2)));
typedef float f32x4 __attribute__((ext_vector_type(4)));
typedef float f32x16 __attribute__((ext_vector_type(16)));
typedef short bf16x8 __attribute__((ext_vector_type(8)));
typedef const __attribute__((address_space(1))) unsigned int* gas_t;
typedef __attribute__((address_space(3))) unsigned int* las_t;

#define GLOAD16(g, l) __builtin_amdgcn_global_load_lds((gas_t)(const void*)(g), (las_t)(void*)(l), 16, 0, 0)

#define LOG2E 1.4426950408889634f
#define MASKC (-144.2695040888963f)
#define SL2E  (0.17677669529663687f * 1.4426950408889634f)

static __device__ __forceinline__ float bf2f(unsigned short u){
  return __uint_as_float(((unsigned)u) << 16);
}
static __device__ __forceinline__ unsigned short f2bf(float f){
  unsigned u = __float_as_uint(f);
  unsigned r = u + 0x7FFFu + ((u >> 16) & 1u);
  return (unsigned short)(r >> 16);
}
static __device__ __forceinline__ unsigned packbf(float a, float b){
  union { __hip_bfloat162 h; unsigned u; } cv;
  cv.h = __float22bfloat162_rn(make_float2(a, b));
  return cv.u;
}
static __device__ __forceinline__ f32x16 zero16(){
  f32x16 z;
  #pragma unroll
  for (int i = 0; i < 16; i++) z[i] = 0.f;
  return z;
}

// ---------------- LN body (MODE0: shift+window gather; MODE1: natural) ----------------
template<int MODE>
static __device__ __forceinline__ void ln_body(const float* __restrict__ in,
                                               const float* __restrict__ g,
                                               const float* __restrict__ bta,
                                               unsigned short* __restrict__ out,
                                               int blk){
  int wave = threadIdx.x >> 6, lane = threadIdx.x & 63;
  int row = blk * 4 + wave;          // < 43904
  size_t srow;
  if (MODE == 0){
    int win = row / 343, n = row - win * 343;
    int b = win >> 6, w64 = win & 63;
    int zw = w64 >> 5, xw = (w64 >> 3) & 3, yw = w64 & 7;
    int i0 = n / 49, nr = n - i0 * 49, i1 = nr / 7, i2 = nr - i1 * 7;
    int zs = zw * 7 + i0 + 3; if (zs >= 14) zs -= 14;
    int xs = xw * 7 + i1 + 3; if (xs >= 28) xs -= 28;
    int ys = yw * 7 + i2 + 3; if (ys >= 56) ys -= 56;
    srow = (size_t)b * 21952 + zs * 1568 + xs * 56 + ys;
  } else {
    srow = (size_t)row;
  }
  const float* p = in + srow * 384;
  float v[6]; float s = 0.f;
  #pragma unroll
  for (int i = 0; i < 3; i++){
    f32x2 t = *(const f32x2*)(p + lane * 2 + i * 128);
    v[2 * i] = t[0]; v[2 * i + 1] = t[1];
    s += t[0] + t[1];
  }
  #pragma unroll
  for (int off = 32; off >= 1; off >>= 1) s += __shfl_xor(s, off);
  float mean = s * (1.f / 384.f);
  float vs = 0.f;
  #pragma unroll
  for (int i = 0; i < 6; i++){ float d = v[i] - mean; vs += d * d; }
  #pragma unroll
  for (int off = 32; off >= 1; off >>= 1) vs += __shfl_xor(vs, off);
  float rstd = rsqrtf(vs * (1.f / 384.f) + 1e-5f);
  unsigned short* o = out + (size_t)row * 384;
  #pragma unroll
  for (int i = 0; i < 3; i++){
    const int c = lane * 2 + i * 128;
    f32x2 gg = *(const f32x2*)(g + c);
    f32x2 bb = *(const f32x2*)(bta + c);
    float a0 = (v[2 * i] - mean) * rstd * gg[0] + bb[0];
    float a1 = (v[2 * i + 1] - mean) * rstd * gg[1] + bb[1];
    *(unsigned*)(&o[c]) = packbf(a0, a1);
  }
}

// ---------------- merged prep bodies ----------------
static __device__ __forceinline__ void wconv_body(const float* __restrict__ in,
                                                  unsigned short* __restrict__ out,
                                                  int K, int N, int bx, int by,
                                                  unsigned short (*t)[33]){
  const int tx = threadIdx.x & 31, ty = threadIdx.x >> 5;
  const int n0 = bx * 32, k0 = by * 32;
  #pragma unroll
  for (int i = 0; i < 4; i++)
    t[ty + 8 * i][tx] = f2bf(in[(size_t)(k0 + ty + 8 * i) * N + n0 + tx]);
  __syncthreads();
  #pragma unroll
  for (int i = 0; i < 4; i++)
    out[(size_t)(n0 + ty + 8 * i) * K + k0 + tx] = t[tx][ty + 8 * i];
}

static __device__ __forceinline__ void biasprep_body(const float* __restrict__ rel,
                                                     unsigned short* __restrict__ biasF16,
                                                     int bx, int plane){
  const int cls = plane / 12, h = plane - cls * 12;
  const int tid = threadIdx.x;
  const int lane = tid >> 2, rb = (tid & 3) * 4;
  const int qt = bx / 11, t = bx - qt * 11;
  const int q = qt * 32 + (lane & 31);
  float v[4];
  #pragma unroll
  for (int j = 0; j < 4; j++){
    const int r = rb + j;
    const int mm = t * 32 + (r & 3) + 8 * (r >> 2) + 4 * (lane >> 5);
    float val;
    if (q >= 343 || mm >= 343) val = -1e30f;
    else {
      int qi0 = q / 49, qr = q - qi0 * 49, qi1 = qr / 7, qi2 = qr - qi1 * 7;
      int mi0 = mm / 49, mr = mm - mi0 * 49, mi1 = mr / 7, mi2 = mr - mi1 * 7;
      int idx = 13 * (qi0 - mi0 + 6) + (qi1 - mi1 + 6) + (qi2 - mi2);
      if (idx < 0) idx += 2197;
      val = rel[idx * 12 + h] * LOG2E;
      int az = (cls & 4) ? (qi0 < 4 ? 1 : 2) : 0;
      int ax = (cls & 2) ? (qi1 < 4 ? 1 : 2) : 0;
      int ay = (cls & 1) ? (qi2 < 4 ? 1 : 2) : 0;
      int bz = (cls & 4) ? (mi0 < 4 ? 1 : 2) : 0;
      int bxm = (cls & 2) ? (mi1 < 4 ? 1 : 2) : 0;
      int by = (cls & 1) ? (mi2 < 4 ? 1 : 2) : 0;
      if (az * 9 + ax * 3 + ay != bz * 9 + bxm * 3 + by) val += MASKC;
    }
    v[j] = val;
  }
  uint2 st;
  st.x = packbf(v[0], v[1]);
  st.y = packbf(v[2], v[3]);
  *(uint2*)(biasF16 + (((size_t)plane * 121 + bx) * 64 + lane) * 16 + rb) = st;
}

static __device__ __forceinline__ void padzero_body(unsigned short* __restrict__ qs2,
                                                    unsigned short* __restrict__ ks2,
                                                    unsigned short* __restrict__ vt2,
                                                    int wh){
  uint4 z = make_uint4(0, 0, 0, 0);
  const size_t base = (size_t)wh * 11264 + 10 * 1024;
  for (int i = threadIdx.x; i < 384; i += 256){
    int arr = i >> 7, slot = i & 127;
    unsigned short* p = (arr == 0 ? qs2 : (arr == 1 ? ks2 : vt2));
    *(uint4*)(p + base + slot * 8) = z;
  }
}

// one launch replaces 7 (incl. LN1, which is independent of all prep work):
// [0,10976) ln0 | [10976,+432) wconv qkv | +144 wconv proj | +576 wconv fc1
// | +576 wconv fc2 | +11616 biasprep | +1536 padzero
__global__ __launch_bounds__(256) void prep_kernel(
    const float* __restrict__ x, const float* __restrict__ n1g,
    const float* __restrict__ n1b, unsigned short* __restrict__ w_win,
    const float* __restrict__ qkv_w, const float* __restrict__ proj_w,
    const float* __restrict__ fc1_w, const float* __restrict__ fc2_w,
    const float* __restrict__ rel,
    unsigned short* __restrict__ wt_qkv, unsigned short* __restrict__ wt_prj,
    unsigned short* __restrict__ wt_fc1, unsigned short* __restrict__ wt_fc2,
    unsigned short* __restrict__ biasF16,
    unsigned short* __restrict__ qs2, unsigned short* __restrict__ ks2,
    unsigned short* __restrict__ vt2){
  __shared__ unsigned short t[32][33];
  int id = blockIdx.x;
  if (id < 10976){ ln_body<0>(x, n1g, n1b, w_win, id); return; }
  id -= 10976;
  if (id < 432){ wconv_body(qkv_w, wt_qkv, 384, 1152, id % 36, id / 36, t); return; }
  id -= 432;
  if (id < 144){ wconv_body(proj_w, wt_prj, 384, 384, id % 12, id / 12, t); return; }
  id -= 144;
  if (id < 576){ wconv_body(fc1_w, wt_fc1, 384, 1536, id % 48, id / 48, t); return; }
  id -= 576;
  if (id < 576){ wconv_body(fc2_w, wt_fc2, 1536, 384, id % 12, id / 12, t); return; }
  id -= 576;
  if (id < 11616){ biasprep_body(rel, biasF16, id % 121, id / 121); return; }
  id -= 11616;
  padzero_body(qs2, ks2, vt2, id);
}

// ---------------- standalone LN (MODE1 only, post-proj) ----------------
__global__ __launch_bounds__(256) void ln1_kernel(const float* __restrict__ in,
                                                  const float* __restrict__ g,
                                                  const float* __restrict__ bta,
                                                  unsigned short* __restrict__ out){
  ln_body<1>(in, g, bta, out, blockIdx.x);
}

// ---------------- GEMM: C[M,N] = A[M,K] @ Bt[N,K]^T, operand-swapped MFMA, BK=64 ----------------
// r18 structure (best measured). nt store only on EPI3 (full-line f32x4, never re-read).
template<int EPI>
__global__ __launch_bounds__(256, 4) void gemm2(
    const unsigned short* __restrict__ A,
    const unsigned short* __restrict__ Bt,
    const float* __restrict__ bias,
    const float* __restrict__ resid,
    void* __restrict__ outp,
    unsigned short* __restrict__ oq,
    unsigned short* __restrict__ ok,
    unsigned short* __restrict__ ov,
    int K, int ldc, int nt_){
  __shared__ unsigned short As[8192];   // 16 KB: 2 ksub x 8 chunks x (16 rows x 32 k)
  __shared__ unsigned short Bs[8192];
  const int nwg = gridDim.x;
  const int qq = nwg >> 3, rr = nwg & 7;
  const int xcd = blockIdx.x & 7, pos = blockIdx.x >> 3;
  const int wgid = (xcd < rr ? xcd * (qq + 1) : rr * (qq + 1) + (xcd - rr) * qq) + pos;
  const int mtile = wgid / nt_, ntile = wgid - mtile * nt_;
  const int r0 = mtile * 128, c0 = ntile * 128;

  const int tid = threadIdx.x, lane = tid & 63, wave = tid >> 6;
  const int wr = (wave >> 1) * 64, wc = (wave & 1) * 64;
  f32x4 acc[4][4];
  #pragma unroll
  for (int mi = 0; mi < 4; mi++)
    #pragma unroll
    for (int ni = 0; ni < 4; ni++) acc[mi][ni] = f32x4{0.f, 0.f, 0.f, 0.f};

  const int srow = lane >> 2;
  const int koff = ((lane & 3) ^ ((lane >> 3) & 3)) * 8;
  const int kkey = (lane >> 1) & 3;

  for (int k0 = 0; k0 < K; k0 += 64){
    __syncthreads();
    #pragma unroll
    for (int i = 0; i < 8; i++){
      const int id = wave + i * 4;            // 0..31
      const int arr = id >> 4;                // 0=A, 1=B
      const int within = id & 15;
      const int ksub = within >> 3;           // 0,1
      const int sub = within & 7;             // 0..7
      const unsigned short* g = (arr ? Bt : A)
          + (size_t)((arr ? c0 : r0) + sub * 16 + srow) * K + k0 + ksub * 32 + koff;
      unsigned short* dst = (arr ? Bs : As) + ksub * 4096 + sub * 512;
      GLOAD16(g, dst);
    }
    __syncthreads();
    #pragma unroll
    for (int ks = 0; ks < 2; ks++){
      bf16x8 af[4], bfr[4];
      #pragma unroll
      for (int mi = 0; mi < 4; mi++)
        af[mi] = *(const bf16x8*)(&As[ks * 4096 + (wr + mi * 16 + (lane & 15)) * 32 + (((lane >> 4) ^ kkey) * 8)]);
      #pragma unroll
      for (int ni = 0; ni < 4; ni++)
        bfr[ni] = *(const bf16x8*)(&Bs[ks * 4096 + (wc + ni * 16 + (lane & 15)) * 32 + (((lane >> 4) ^ kkey) * 8)]);
      #pragma unroll
      for (int mi = 0; mi < 4; mi++)
        #pragma unroll
        for (int ni = 0; ni < 4; ni++)
          acc[mi][ni] = __builtin_amdgcn_mfma_f32_16x16x32_bf16(bfr[ni], af[mi], acc[mi][ni], 0, 0, 0);
    }
  }

  // ---- direct-from-acc epilogue: thread owns (row, 4 consecutive cols) per (mi,ni) ----
  const int lrow = lane & 15;
  const int cq4  = (lane >> 4) << 2;
  #pragma unroll
  for (int mi = 0; mi < 4; mi++){
    const int row = r0 + wr + mi * 16 + lrow;
    int win, m, t, mloc, vh2;
    size_t sdst;
    if (EPI == 0 || EPI == 1){ win = row / 343; m = row - win * 343; }
    if (EPI == 0){
      t = m >> 5; mloc = m & 31;
      vh2 = ((m >> 4) & 1) * 512 + ((m >> 3) & 1) * 256 + (m & 7);
    }
    if (EPI == 1){
      const int b = win >> 6, w64 = win & 63;
      const int zw = w64 >> 5, xw = (w64 >> 3) & 3, yw = w64 & 7;
      const int i0 = m / 49, nr = m - i0 * 49, i1 = nr / 7, i2 = nr - i1 * 7;
      int zf = zw * 7 + i0 + 3; if (zf >= 14) zf -= 14;
      int xf = xw * 7 + i1 + 3; if (xf >= 28) xf -= 28;
      int yf = yw * 7 + i2 + 3; if (yf >= 56) yf -= 56;
      sdst = ((size_t)b * 21952 + zf * 1568 + xf * 56 + yf) * 384;
    }
    #pragma unroll
    for (int ni = 0; ni < 4; ni++){
      const int colb = c0 + wc + ni * 16 + cq4;      // 4 consecutive cols
      float v[4];
      #pragma unroll
      for (int j = 0; j < 4; j++) v[j] = acc[mi][ni][j] + bias[colb + j];
      if (EPI == 2){
        #pragma unroll
        for (int j = 0; j < 4; j++)
          v[j] = v[j] * __builtin_amdgcn_rcpf(1.0f + exp2f(v[j] * -2.4554669f));
        uint2 st; st.x = packbf(v[0], v[1]); st.y = packbf(v[2], v[3]);
        *(uint2*)((unsigned short*)outp + (size_t)row * ldc + colb) = st;
      } else if (EPI == 3){
        const float* rsd = resid + (size_t)row * ldc + colb;
        f32x4 q = *(const f32x4*)rsd;
        f32x4 o4; o4[0] = v[0] + q[0]; o4[1] = v[1] + q[1];
        o4[2] = v[2] + q[2]; o4[3] = v[3] + q[3];
        __builtin_nontemporal_store(o4, (f32x4*)((float*)outp + (size_t)row * ldc + colb));
      } else if (EPI == 1){
        const float* rsd = resid + sdst + colb;
        f32x4 q = *(const f32x4*)rsd;
        f32x4 o4; o4[0] = v[0] + q[0]; o4[1] = v[1] + q[1];
        o4[2] = v[2] + q[2]; o4[3] = v[3] + q[3];
        *(f32x4*)((float*)outp + sdst + colb) = o4;
      } else { // EPI == 0
        if (c0 < 384){
          #pragma unroll
          for (int j = 0; j < 4; j++) v[j] *= SL2E;
          const int d = colb, h = d >> 5, dd = d & 31;
          const size_t off = (size_t)(win * 12 + h) * 11264
              + (size_t)(t * 1024 + ((dd >> 4) & 1) * 512 + ((dd >> 3) & 1) * 256 + mloc * 8 + (dd & 7));
          uint2 st; st.x = packbf(v[0], v[1]); st.y = packbf(v[2], v[3]);
          *(uint2*)(oq + off) = st;
        } else if (c0 < 768){
          const int d = colb - 384, h = d >> 5, dd = d & 31;
          const size_t off = (size_t)(win * 12 + h) * 11264
              + (size_t)(t * 1024 + ((dd >> 4) & 1) * 512 + ((dd >> 3) & 1) * 256 + mloc * 8 + (dd & 7));
          uint2 st; st.x = packbf(v[0], v[1]); st.y = packbf(v[2], v[3]);
          *(uint2*)(ok + off) = st;
        } else {
          const int d = colb - 768, h = d >> 5, dd = d & 31;
          const size_t off = (size_t)(win * 12 + h) * 11264 + (size_t)(t * 1024 + vh2);
          #pragma unroll
          for (int j = 0; j < 4; j++)
            ov[off + (size_t)(dd + j) * 8] = f2bf(v[j]);
        }
      }
    }
  }
}

// ---------------- MFMA attention v4: bf16 bias/mask unpacked as MFMA C-in; in-reg P ----
__global__ __launch_bounds__(256, 4) void attn4_kernel(
    const unsigned short* __restrict__ qs2,
    const unsigned short* __restrict__ ks2,
    const unsigned short* __restrict__ vt2,
    const unsigned short* __restrict__ biasF16,
    unsigned short* __restrict__ out){
  __shared__ unsigned short Ks[11264];     // 22 KB, chunk-packed
  const int wh = blockIdx.x;
  const int win = wh / 12, h = wh - win * 12;
  const int tid = threadIdx.x, wave = tid >> 6, lane = tid & 63;
  const int ln = lane & 31, hh = lane >> 5;

  const unsigned short* ksrc = ks2 + (size_t)wh * 11264;
  for (int c = wave; c < 22; c += 4)
    GLOAD16(ksrc + c * 512 + lane * 8, &Ks[c * 512]);

  const int w64 = win & 63;
  const int cls = (((w64 >> 5) & 1) ? 4 : 0) | ((((w64 >> 3) & 3) == 3) ? 2 : 0) | (((w64 & 7) == 7) ? 1 : 0);
  __syncthreads();

  const unsigned short* qbase = qs2 + (size_t)wh * 11264;
  const unsigned short* vbase = vt2 + (size_t)wh * 11264;
  const unsigned short* bbase = biasF16 + (size_t)(cls * 12 + h) * 123904 + lane * 16;

  for (int qt = wave; qt < 11; qt += 4){
    const bf16x8 bq0 = *(const bf16x8*)(qbase + qt * 1024 + hh * 256 + ln * 8);
    const bf16x8 bq1 = *(const bf16x8*)(qbase + qt * 1024 + 512 + hh * 256 + ln * 8);
    const unsigned short* brow = bbase + (size_t)qt * 11264;   // 11 tiles x 1024 ushort

    f32x16 o = zero16();
    float sum = 0.f;
    // prefetch t=0
    bf16x8 nbv0 = *(const bf16x8*)(vbase + hh * 256 + ln * 8);
    bf16x8 nbv1 = *(const bf16x8*)(vbase + 512 + hh * 256 + ln * 8);
    uint4 nbw0 = *(const uint4*)(brow);
    uint4 nbw1 = *(const uint4*)(brow + 8);

    for (int t = 0; t < 11; t++){
      const bf16x8 bv0 = nbv0, bv1 = nbv1;
      unsigned w[8];
      w[0] = nbw0.x; w[1] = nbw0.y; w[2] = nbw0.z; w[3] = nbw0.w;
      w[4] = nbw1.x; w[5] = nbw1.y; w[6] = nbw1.z; w[7] = nbw1.w;
      if (t < 10){
        const unsigned short* vnext = vbase + (t + 1) * 1024;
        nbv0 = *(const bf16x8*)(vnext + hh * 256 + ln * 8);
        nbv1 = *(const bf16x8*)(vnext + 512 + hh * 256 + ln * 8);
        nbw0 = *(const uint4*)(brow + (t + 1) * 1024);
        nbw1 = *(const uint4*)(brow + (t + 1) * 1024 + 8);
      }
      f32x16 acc;                            // C-in = bias + mask (log2-domain), bf16-unpacked
      #pragma unroll
      for (int j = 0; j < 8; j++){
        acc[2 * j]     = __uint_as_float(w[j] << 16);
        acc[2 * j + 1] = __uint_as_float(w[j] & 0xffff0000u);
      }
      const bf16x8 ka0 = *(const bf16x8*)(&Ks[t * 1024 + hh * 256 + ln * 8]);
      const bf16x8 ka1 = *(const bf16x8*)(&Ks[t * 1024 + 512 + hh * 256 + ln * 8]);
      acc = __builtin_amdgcn_mfma_f32_32x32x16_bf16(ka0, bq0, acc, 0, 0, 0);
      acc = __builtin_amdgcn_mfma_f32_32x32x16_bf16(ka1, bq1, acc, 0, 0, 0);

      float pv[16];
      #pragma unroll
      for (int r = 0; r < 16; r++){
        const float e = exp2f(acc[r]);
        sum += e;
        pv[r] = e;
      }
      // in-register P -> A-frag via cvt_pk + permlane32_swap (T12)
      unsigned a0 = packbf(pv[0], pv[1]),  b0 = packbf(pv[4], pv[5]);
      unsigned a1 = packbf(pv[2], pv[3]),  b1 = packbf(pv[6], pv[7]);
      unsigned a2 = packbf(pv[8], pv[9]),  b2 = packbf(pv[12], pv[13]);
      unsigned a3 = packbf(pv[10], pv[11]), b3 = packbf(pv[14], pv[15]);
      asm volatile("v_permlane32_swap_b32 %0, %1" : "+v"(a0), "+v"(b0));
      asm volatile("v_permlane32_swap_b32 %0, %1" : "+v"(a1), "+v"(b1));
      asm volatile("v_permlane32_swap_b32 %0, %1" : "+v"(a2), "+v"(b2));
      asm volatile("v_permlane32_swap_b32 %0, %1" : "+v"(a3), "+v"(b3));
      union { unsigned u[4]; bf16x8 v; } p0c, p1c;
      p0c.u[0] = a0; p0c.u[1] = a1; p0c.u[2] = b0; p0c.u[3] = b1;
      p1c.u[0] = a2; p1c.u[1] = a3; p1c.u[2] = b2; p1c.u[3] = b3;
      o = __builtin_amdgcn_mfma_f32_32x32x16_bf16(p0c.v, bv0, o, 0, 0, 0);
      o = __builtin_amdgcn_mfma_f32_32x32x16_bf16(p1c.v, bv1, o, 0, 0, 0);
    }
    sum += __shfl_xor(sum, 32);
    const float inv = 1.f / sum;   // lane ln holds inv for q-local = ln
    #pragma unroll
    for (int r = 0; r < 16; r++){
      const int qloc = (r & 3) + 8 * (r >> 2) + 4 * hh;
      const float iv = __shfl(inv, qloc);
      const int qg = qt * 32 + qloc;
      if (qg < 343)
        out[((size_t)win * 343 + qg) * 384 + h * 32 + ln] = f2bf(o[r] * iv);
    }
  }
}

// ---------------- host launcher ----------------
extern "C" void kernel_launch(void* const* d_in, const int* in_sizes, int n_in,
                              void* d_out, int out_size, void* d_ws, size_t ws_size,
                              hipStream_t stream){
  const float* x      = (const float*)d_in[0];
  const float* n1g    = (const float*)d_in[1];
  const float* n1b    = (const float*)d_in[2];
  const float* qkv_w  = (const float*)d_in[3];
  const float* qkv_b  = (const float*)d_in[4];
  const float* proj_w = (const float*)d_in[5];
  const float* proj_b = (const float*)d_in[6];
  const float* rel    = (const float*)d_in[7];
  const float* n2g    = (const float*)d_in[8];
  const float* n2b    = (const float*)d_in[9];
  const float* fc1_w  = (const float*)d_in[10];
  const float* fc1_b  = (const float*)d_in[11];
  const float* fc2_w  = (const float*)d_in[12];
  const float* fc2_b  = (const float*)d_in[13];
  float* out = (float*)d_out;

  char* ws = (char*)d_ws;
  // Region plan (bytes), high-water 239,566,848:
  // [0, 33.7M)            w_win bf16 [43904][384]      -- reused as hidden bf16 (0..134.9M)
  // [33.7M, 68.3M)        qs2 ; [68.3M, 102.9M) ks2 ; [102.9M, 137.5M) vt2   -- dead after attn
  // [134.9M, 202.3M)      x2 f32 (written post-attn); pre-attn holds biasF16 @137.5M (23.8MB)
  // [202.3M, 236.0M)      att bf16 -- reused as ln2
  // [236.0M, 239.6M)      bf16 transposed weights
  // All attn-read regions (incl. pads) rewritten EVERY call.
  unsigned short* w_win  = (unsigned short*)(ws + 0);
  unsigned short* hidden = (unsigned short*)(ws + 0);
  unsigned short* qs2    = (unsigned short*)(ws + 33718272ull);
  unsigned short* ks2    = (unsigned short*)(ws + 68321280ull);
  unsigned short* vt2    = (unsigned short*)(ws + 102924288ull);
  float*          x2     = (float*)(ws + 134873088ull);
  unsigned short* biasF16= (unsigned short*)(ws + 137527296ull);  // 23,789,568 B
  unsigned short* att    = (unsigned short*)(ws + 202309632ull);
  unsigned short* ln2    = att;
  unsigned short* wt_qkv = (unsigned short*)(ws + 236027904ull);
  unsigned short* wt_prj = (unsigned short*)(ws + 236912640ull);
  unsigned short* wt_fc1 = (unsigned short*)(ws + 237207552ull);
  unsigned short* wt_fc2 = (unsigned short*)(ws + 238387200ull);

  prep_kernel<<<25856, 256, 0, stream>>>(x, n1g, n1b, w_win,
                                         qkv_w, proj_w, fc1_w, fc2_w, rel,
                                         wt_qkv, wt_prj, wt_fc1, wt_fc2, biasF16,
                                         qs2, ks2, vt2);

  gemm2<0><<<343 * 9, 256, 0, stream>>>(w_win, wt_qkv, qkv_b, nullptr, nullptr,
                                        qs2, ks2, vt2, 384, 0, 9);
  attn4_kernel<<<1536, 256, 0, stream>>>(qs2, ks2, vt2, biasF16, att);
  gemm2<1><<<343 * 3, 256, 0, stream>>>(att, wt_prj, proj_b, x, x2,
                                        nullptr, nullptr, nullptr, 384, 384, 3);
  ln1_kernel<<<10976, 256, 0, stream>>>(x2, n2g, n2b, ln2);
  gemm2<2><<<343 * 12, 256, 0, stream>>>(ln2, wt_fc1, fc1_b, nullptr, hidden,
                                         nullptr, nullptr, nullptr, 384, 1536, 12);
  gemm2<3><<<343 * 3, 256, 0, stream>>>(hidden, wt_fc2, fc2_b, x2, out,
                                        nullptr, nullptr, nullptr, 1536, 384, 3);
}